// Round 1
// baseline (2431.175 us; speedup 1.0000x reference)
//
#include <hip/hip_runtime.h>
#include <hip/hip_bf16.h>

// Sizes (compile-time constants for this problem)
#define B_TOK   4096
#define D_DIM   1024
#define E_NUM   8
#define K_TOP   2
#define HID_DIM 512
#define RH_DIM  256
#define EMB_DIM 32
#define NPAIR   (B_TOK * K_TOP)   // 8192

__device__ inline float apply_act(float v, int a) {
    if (a == 0 || a == 2) return 1.f / (1.f + expf(-v));        // sigmoid
    if (a == 1) return fmaxf(v, 0.f) + log1pf(expf(-fabsf(v))); // softplus (stable)
    return v;                                                    // identity
}

// ---------------- routing const vector: br1 + le@Wr1[2048:2080] + pe@Wr1[2080:2112]
__global__ void k_rconst(const float* __restrict__ layer_emb,
                         const float* __restrict__ phase_emb,
                         const int* __restrict__ lidx,
                         const float* __restrict__ Wr1,
                         const float* __restrict__ br1,
                         float* __restrict__ rconst) {
    int j = threadIdx.x;  // 256
    int li = lidx[0];
    float acc = br1[j];
    for (int t = 0; t < EMB_DIM; ++t)
        acc += layer_emb[li * EMB_DIM + t] * Wr1[(2048 + t) * RH_DIM + j];
    for (int t = 0; t < EMB_DIM; ++t)
        acc += phase_emb[t] * Wr1[(2080 + t) * RH_DIM + j];
    rconst[j] = acc;
}

// ---------------- routing tail: LN + gelu + logits + top2 + softmax + gather lists
__global__ void k_route(const float* __restrict__ rpre,
                        const float* __restrict__ lnr_g, const float* __restrict__ lnr_b,
                        const float* __restrict__ Wr2, const float* __restrict__ br2,
                        int* __restrict__ pair_e, float* __restrict__ pair_w,
                        int* __restrict__ lists, int* __restrict__ counts) {
    int b = blockIdx.x, t = threadIdx.x;  // 256 threads
    __shared__ float sv[RH_DIM];
    __shared__ float a1[4], a2[4], mv[2], lg[E_NUM];

    float y = rpre[(size_t)b * RH_DIM + t];
    float s1 = y, s2 = y * y;
    for (int o = 32; o; o >>= 1) { s1 += __shfl_down(s1, o); s2 += __shfl_down(s2, o); }
    if ((t & 63) == 0) { a1[t >> 6] = s1; a2[t >> 6] = s2; }
    __syncthreads();
    if (t == 0) {
        float S1 = a1[0] + a1[1] + a1[2] + a1[3];
        float S2 = a2[0] + a2[1] + a2[2] + a2[3];
        float mu = S1 / 256.f;
        mv[0] = mu;
        mv[1] = rsqrtf(S2 / 256.f - mu * mu + 1e-5f);
    }
    __syncthreads();
    float n = (y - mv[0]) * mv[1] * lnr_g[t] + lnr_b[t];
    sv[t] = 0.5f * n * (1.f + erff(n * 0.70710678118654752f));
    __syncthreads();
    if (t < E_NUM) {
        float acc = br2[t];
        for (int j = 0; j < RH_DIM; ++j) acc += sv[j] * Wr2[j * E_NUM + t];
        lg[t] = acc;
    }
    __syncthreads();
    if (t == 0) {
        float v0 = -1e30f; int i0 = 0;
        for (int e = 0; e < E_NUM; ++e) if (lg[e] > v0) { v0 = lg[e]; i0 = e; }
        float v1 = -1e30f; int i1 = 0;
        for (int e = 0; e < E_NUM; ++e) if (e != i0 && lg[e] > v1) { v1 = lg[e]; i1 = e; }
        float e1 = expf(v1 - v0);
        float w0 = 1.f / (1.f + e1);
        float w1 = e1 / (1.f + e1);
        pair_e[2 * b] = i0;  pair_e[2 * b + 1] = i1;
        pair_w[2 * b] = w0;  pair_w[2 * b + 1] = w1;
        int p0 = atomicAdd(&counts[i0], 1); lists[i0 * B_TOK + p0] = 2 * b;
        int p1 = atomicAdd(&counts[i1], 1); lists[i1 * B_TOK + p1] = 2 * b + 1;
    }
}

// ---------------- LN + gelu over hid rows (512), in place
__global__ void k_lngelu(float* __restrict__ hid, const int* __restrict__ pair_e,
                         const float* __restrict__ g, const float* __restrict__ bb) {
    int p = blockIdx.x, t = threadIdx.x;  // 256 threads, 512 cols
    float* row = hid + (size_t)p * HID_DIM;
    float y0 = row[t], y1 = row[t + 256];
    float s1 = y0 + y1, s2 = y0 * y0 + y1 * y1;
    for (int o = 32; o; o >>= 1) { s1 += __shfl_down(s1, o); s2 += __shfl_down(s2, o); }
    __shared__ float a1[4], a2[4], mv[2];
    if ((t & 63) == 0) { a1[t >> 6] = s1; a2[t >> 6] = s2; }
    __syncthreads();
    if (t == 0) {
        float S1 = a1[0] + a1[1] + a1[2] + a1[3];
        float S2 = a2[0] + a2[1] + a2[2] + a2[3];
        float mu = S1 / 512.f;
        mv[0] = mu;
        mv[1] = rsqrtf(S2 / 512.f - mu * mu + 1e-5f);
    }
    __syncthreads();
    int e = pair_e[p];
    const float* ge = g + e * HID_DIM;
    const float* be = bb + e * HID_DIM;
    float mu = mv[0], ir = mv[1];
    float n0 = (y0 - mu) * ir * ge[t] + be[t];
    float n1 = (y1 - mu) * ir * ge[t + 256] + be[t + 256];
    row[t]       = 0.5f * n0 * (1.f + erff(n0 * 0.70710678118654752f));
    row[t + 256] = 0.5f * n1 * (1.f + erff(n1 * 0.70710678118654752f));
}

// ---------------- generic fp32 tiled GEMM, gathered rows, per-expert weights
// MODE 0: C[p] = acc + bias[e]    MODE 2: atomicAdd(out[token], w*act(acc+bias))
// USE_HX: A-row is [h | x] concat  ROWSHIFT: pair->token for A row
template<int MODE, bool USE_HX, int ROWSHIFT>
__global__ __launch_bounds__(256)
void k_gemm(const float* __restrict__ A, const float* __restrict__ Ax, int lda,
            const float* __restrict__ Wbase, size_t wstride,
            const float* __restrict__ bias, int bstride,
            float* __restrict__ C, int ldc,
            const int* __restrict__ lists, const int* __restrict__ counts,
            int M, int N, int Kdim,
            float* __restrict__ outp, const float* __restrict__ pw, int actType) {
    const int e = blockIdx.z;
    const int cnt = counts ? counts[e] : M;
    const int m0 = blockIdx.y * 64;
    if (m0 >= cnt) return;
    const int n0 = blockIdx.x * 64;
    const float* W = Wbase + (size_t)e * wstride;
    const int* list = lists ? (lists + e * B_TOK) : nullptr;

    __shared__ float As[16][68];
    __shared__ float Bs[16][64];

    const int tid = threadIdx.x;
    const int am = tid >> 2;            // 0..63 A row within tile
    const int ak = (tid & 3) << 2;      // 0,4,8,12
    const int bk = tid >> 4;            // 0..15
    const int bn = (tid & 15) << 2;     // 0..60
    const int mb = (tid >> 4) << 2;     // acc rows base
    const int nb = (tid & 15) << 2;     // acc cols base

    int arow = m0 + am;
    bool av = arow < cnt;
    size_t abase = 0;
    if (av) {
        int p = list ? list[arow] : arow;
        int r = ROWSHIFT ? (p >> 1) : p;
        abase = (size_t)r * (USE_HX ? 1024 : lda);
    }

    float acc[4][4] = {{0.f}};

    for (int k0 = 0; k0 < Kdim; k0 += 16) {
        float4 avv = make_float4(0.f, 0.f, 0.f, 0.f);
        if (av) {
            int kk = k0 + ak;
            const float* src;
            if (USE_HX) src = (kk < 1024) ? (A + abase + kk) : (Ax + abase + kk - 1024);
            else        src = A + abase + kk;
            avv = *(const float4*)src;
        }
        As[ak + 0][am] = avv.x; As[ak + 1][am] = avv.y;
        As[ak + 2][am] = avv.z; As[ak + 3][am] = avv.w;
        *(float4*)&Bs[bk][bn] = *(const float4*)(W + (size_t)(k0 + bk) * N + n0 + bn);
        __syncthreads();
#pragma unroll
        for (int kk = 0; kk < 16; ++kk) {
            float4 a4 = *(float4*)&As[kk][mb];
            float4 b4 = *(float4*)&Bs[kk][nb];
            acc[0][0] += a4.x * b4.x; acc[0][1] += a4.x * b4.y; acc[0][2] += a4.x * b4.z; acc[0][3] += a4.x * b4.w;
            acc[1][0] += a4.y * b4.x; acc[1][1] += a4.y * b4.y; acc[1][2] += a4.y * b4.z; acc[1][3] += a4.y * b4.w;
            acc[2][0] += a4.z * b4.x; acc[2][1] += a4.z * b4.y; acc[2][2] += a4.z * b4.z; acc[2][3] += a4.z * b4.w;
            acc[3][0] += a4.w * b4.x; acc[3][1] += a4.w * b4.y; acc[3][2] += a4.w * b4.z; acc[3][3] += a4.w * b4.w;
        }
        __syncthreads();
    }

#pragma unroll
    for (int i = 0; i < 4; ++i) {
        int r = m0 + mb + i;
        if (r >= cnt) break;
        int p = list ? list[r] : r;
        if (MODE == 0) {
            float4 bv = *(const float4*)(bias + (size_t)e * bstride + n0 + nb);
            float4 o4;
            o4.x = acc[i][0] + bv.x; o4.y = acc[i][1] + bv.y;
            o4.z = acc[i][2] + bv.z; o4.w = acc[i][3] + bv.w;
            *(float4*)(C + (size_t)p * ldc + n0 + nb) = o4;
        } else {
            int token = p >> 1;
            float wgt = pw[p];
#pragma unroll
            for (int j = 0; j < 4; ++j) {
                float v = acc[i][j] + bias[(size_t)e * bstride + n0 + nb + j];
                v = apply_act(v, actType);
                atomicAdd(outp + (size_t)token * D_DIM + n0 + nb + j, wgt * v);
            }
        }
    }
}

extern "C" void kernel_launch(void* const* d_in, const int* in_sizes, int n_in,
                              void* d_out, int out_size, void* d_ws, size_t ws_size,
                              hipStream_t stream) {
    const float* h         = (const float*)d_in[0];
    const float* x         = (const float*)d_in[1];
    const int*   lidx      = (const int*)d_in[2];
    const float* layer_emb = (const float*)d_in[3];
    const float* phase_emb = (const float*)d_in[4];
    const float* Wr1       = (const float*)d_in[5];
    const float* br1       = (const float*)d_in[6];
    const float* lnr_g     = (const float*)d_in[7];
    const float* lnr_b     = (const float*)d_in[8];
    const float* Wr2       = (const float*)d_in[9];
    const float* br2       = (const float*)d_in[10];
    const float* W1        = (const float*)d_in[11];
    const float* b1        = (const float*)d_in[12];
    const float* ln1g      = (const float*)d_in[13];
    const float* ln1b      = (const float*)d_in[14];
    const float* W2        = (const float*)d_in[15];
    const float* b2        = (const float*)d_in[16];
    const float* Wa        = (const float*)d_in[17];
    const float* ba        = (const float*)d_in[18];
    const float* Wb_       = (const float*)d_in[19];
    const float* bbv       = (const float*)d_in[20];
    const float* Wg        = (const float*)d_in[21];
    const float* bg        = (const float*)d_in[22];
    const float* Wv        = (const float*)d_in[23];
    const float* bv        = (const float*)d_in[24];
    float* out = (float*)d_out;

    char* ws = (char*)d_ws;
    size_t off = 0;
    auto alloc = [&](size_t nb) { void* p = ws + off; off = (off + nb + 255) & ~(size_t)255; return p; };
    float* rconst = (float*)alloc(RH_DIM * 4);
    float* rpre   = (float*)alloc((size_t)B_TOK * RH_DIM * 4);
    int*   pair_e = (int*)alloc(NPAIR * 4);
    float* pair_w = (float*)alloc(NPAIR * 4);
    int*   counts = (int*)alloc(64);
    int*   lists  = (int*)alloc((size_t)E_NUM * B_TOK * 4);
    float* hid    = (float*)alloc((size_t)NPAIR * HID_DIM * 4);
    float* feats  = (float*)alloc((size_t)NPAIR * 4096 * 4);

    (void)hipMemsetAsync(d_out, 0, (size_t)out_size * 4, stream);
    (void)hipMemsetAsync(counts, 0, 64, stream);

    dim3 blk(256);

    k_rconst<<<1, 256, 0, stream>>>(layer_emb, phase_emb, lidx, Wr1, br1, rconst);

    // routing GEMM: rpre(4096x256) = [h|x] @ Wr1[0:2048] + rconst
    k_gemm<0, true, 0><<<dim3(RH_DIM / 64, B_TOK / 64, 1), blk, 0, stream>>>(
        h, x, 0, Wr1, 0, rconst, 0, rpre, RH_DIM,
        nullptr, nullptr, B_TOK, RH_DIM, 2048, nullptr, nullptr, 0);

    k_route<<<B_TOK, 256, 0, stream>>>(rpre, lnr_g, lnr_b, Wr2, br2,
                                       pair_e, pair_w, lists, counts);

    // layer1: hid[p](512) = [h|x][token] @ W1[e] + b1[e]
    k_gemm<0, true, 1><<<dim3(HID_DIM / 64, 64, E_NUM), blk, 0, stream>>>(
        h, x, 0, W1, (size_t)2048 * HID_DIM, b1, HID_DIM, hid, HID_DIM,
        lists, counts, 0, HID_DIM, 2048, nullptr, nullptr, 0);

    k_lngelu<<<NPAIR, 256, 0, stream>>>(hid, pair_e, ln1g, ln1b);

    // layer2: feats[p](4096) = hid[p] @ W2[e] + b2[e]
    k_gemm<0, false, 0><<<dim3(4096 / 64, 64, E_NUM), blk, 0, stream>>>(
        hid, nullptr, HID_DIM, W2, (size_t)HID_DIM * 4096, b2, 4096, feats, 4096,
        lists, counts, 0, 4096, HID_DIM, nullptr, nullptr, 0);

    // layer3 x4: out[o][token] += w * act(feats[p][o*1024:+1024] @ Wact[e] + bact[e])
    const float* Ws[4] = {Wa, Wb_, Wg, Wv};
    const float* bs[4] = {ba, bbv, bg, bv};
    const int acts[4] = {0, 1, 2, 3};
    for (int o = 0; o < 4; ++o) {
        k_gemm<2, false, 0><<<dim3(D_DIM / 64, 64, E_NUM), blk, 0, stream>>>(
            feats + (size_t)o * D_DIM, nullptr, 4096, Ws[o], (size_t)D_DIM * D_DIM,
            bs[o], D_DIM, nullptr, 0,
            lists, counts, 0, D_DIM, D_DIM,
            out + (size_t)o * B_TOK * D_DIM, pair_w, acts[o]);
    }
}

// Round 2
// 770.907 us; speedup vs baseline: 3.1537x; 3.1537x over previous
//
#include <hip/hip_runtime.h>
#include <hip/hip_bf16.h>

#define B_TOK   4096
#define D_DIM   1024
#define E_NUM   8
#define HID_DIM 512
#define RH_DIM  256
#define EMB_DIM 32
#define NPAIR   (B_TOK * 2)   // 8192

typedef __attribute__((ext_vector_type(8))) short    bf16x8;
typedef __attribute__((ext_vector_type(8))) unsigned short u16x8;
typedef __attribute__((ext_vector_type(4))) float    f32x4;

__device__ __forceinline__ unsigned short f2bf(float f) {
    union { float f; unsigned u; } v; v.f = f;
    unsigned r = (v.u + 0x7fffu + ((v.u >> 16) & 1u)) >> 16;
    return (unsigned short)r;
}
__device__ __forceinline__ float bf2f(unsigned short b) {
    union { unsigned u; float f; } v; v.u = ((unsigned)b) << 16;
    return v.f;
}

__device__ __forceinline__ void glds16(const void* g, void* l) {
    __builtin_amdgcn_global_load_lds(
        (const __attribute__((address_space(1))) unsigned int*)g,
        (__attribute__((address_space(3))) unsigned int*)l, 16, 0, 0);
}

__device__ inline float apply_act(float v, int a) {
    if (a == 0 || a == 2) return 1.f / (1.f + expf(-v));        // sigmoid
    if (a == 1) return fmaxf(v, 0.f) + log1pf(expf(-fabsf(v))); // softplus
    return v;                                                    // identity
}

// ---------------- hx -> bf16 (hi + lo split), layout [token][2048]
__global__ void k_hxbf(const float* __restrict__ h, const float* __restrict__ x,
                       unsigned short* __restrict__ hi, unsigned short* __restrict__ lo) {
    int gid = blockIdx.x * 256 + threadIdx.x;      // one 8-elem chunk
    int token = gid >> 8;                          // 2048/8 = 256 chunks/row
    int c0 = (gid & 255) * 8;
    const float* src = (c0 < 1024) ? (h + (size_t)token * 1024 + c0)
                                   : (x + (size_t)token * 1024 + c0 - 1024);
    u16x8 oh, ol;
#pragma unroll
    for (int j = 0; j < 8; ++j) {
        float f = src[j];
        unsigned short hb = f2bf(f);
        oh[j] = hb;
        ol[j] = f2bf(f - bf2f(hb));
    }
    size_t o = (size_t)gid * 8;
    *(u16x8*)(hi + o) = oh;
    *(u16x8*)(lo + o) = ol;
}

// ---------------- W [K][N] fp32 -> permuted bf16 [K/8][N][8]
template<bool SPLIT>
__global__ void k_convW(const float* __restrict__ in, unsigned short* __restrict__ oh,
                        unsigned short* __restrict__ ol, int K, int N) {
    size_t base = (size_t)blockIdx.z * K * N;
    int n  = blockIdx.x * 256 + threadIdx.x;
    int kg = blockIdx.y;
    const float* ip = in + base + (size_t)kg * 8 * N + n;
    u16x8 hv, lv;
#pragma unroll
    for (int j = 0; j < 8; ++j) {
        float f = ip[(size_t)j * N];
        unsigned short hb = f2bf(f);
        hv[j] = hb;
        if (SPLIT) lv[j] = f2bf(f - bf2f(hb));
    }
    size_t o = base + ((size_t)kg * N + n) * 8;
    *(u16x8*)(oh + o) = hv;
    if (SPLIT) *(u16x8*)(ol + o) = lv;
}

// ---------------- routing const: br1 + le@Wr1[2048:2080] + pe@Wr1[2080:2112]
__global__ void k_rconst(const float* __restrict__ layer_emb,
                         const float* __restrict__ phase_emb,
                         const int* __restrict__ lidx,
                         const float* __restrict__ Wr1,
                         const float* __restrict__ br1,
                         float* __restrict__ rconst) {
    int j = threadIdx.x;
    int li = lidx[0];
    float acc = br1[j];
    for (int t = 0; t < EMB_DIM; ++t)
        acc += layer_emb[li * EMB_DIM + t] * Wr1[(2048 + t) * RH_DIM + j];
    for (int t = 0; t < EMB_DIM; ++t)
        acc += phase_emb[t] * Wr1[(2080 + t) * RH_DIM + j];
    rconst[j] = acc;
}

// ---------------- routing tail: LN + gelu + logits + top2 + softmax + lists
__global__ void k_route(const float* __restrict__ rpre,
                        const float* __restrict__ lnr_g, const float* __restrict__ lnr_b,
                        const float* __restrict__ Wr2, const float* __restrict__ br2,
                        int* __restrict__ pair_e, float* __restrict__ pair_w,
                        int* __restrict__ lists, int* __restrict__ counts) {
    int b = blockIdx.x, t = threadIdx.x;
    __shared__ float sv[RH_DIM];
    __shared__ float a1[4], a2[4], mv[2], lg[E_NUM];

    float y = rpre[(size_t)b * RH_DIM + t];
    float s1 = y, s2 = y * y;
    for (int o = 32; o; o >>= 1) { s1 += __shfl_down(s1, o); s2 += __shfl_down(s2, o); }
    if ((t & 63) == 0) { a1[t >> 6] = s1; a2[t >> 6] = s2; }
    __syncthreads();
    if (t == 0) {
        float S1 = a1[0] + a1[1] + a1[2] + a1[3];
        float S2 = a2[0] + a2[1] + a2[2] + a2[3];
        float mu = S1 / 256.f;
        mv[0] = mu;
        mv[1] = rsqrtf(S2 / 256.f - mu * mu + 1e-5f);
    }
    __syncthreads();
    float n = (y - mv[0]) * mv[1] * lnr_g[t] + lnr_b[t];
    sv[t] = 0.5f * n * (1.f + erff(n * 0.70710678118654752f));
    __syncthreads();
    if (t < E_NUM) {
        float acc = br2[t];
        for (int j = 0; j < RH_DIM; ++j) acc += sv[j] * Wr2[j * E_NUM + t];
        lg[t] = acc;
    }
    __syncthreads();
    if (t == 0) {
        float v0 = -1e30f; int i0 = 0;
        for (int e = 0; e < E_NUM; ++e) if (lg[e] > v0) { v0 = lg[e]; i0 = e; }
        float v1 = -1e30f; int i1 = 0;
        for (int e = 0; e < E_NUM; ++e) if (e != i0 && lg[e] > v1) { v1 = lg[e]; i1 = e; }
        float e1 = expf(v1 - v0);
        pair_e[2 * b] = i0;  pair_e[2 * b + 1] = i1;
        pair_w[2 * b] = 1.f / (1.f + e1);
        pair_w[2 * b + 1] = e1 / (1.f + e1);
        int p0 = atomicAdd(&counts[i0], 1); lists[i0 * B_TOK + p0] = 2 * b;
        int p1 = atomicAdd(&counts[i1], 1); lists[i1 * B_TOK + p1] = 2 * b + 1;
    }
}

// ---------------- LN + gelu over hid rows (512), fp32 in -> bf16 out
__global__ void k_lngelu(const float* __restrict__ hid, unsigned short* __restrict__ hidb,
                         const int* __restrict__ pair_e,
                         const float* __restrict__ g, const float* __restrict__ bb) {
    int p = blockIdx.x, t = threadIdx.x;
    const float* row = hid + (size_t)p * HID_DIM;
    float y0 = row[t], y1 = row[t + 256];
    float s1 = y0 + y1, s2 = y0 * y0 + y1 * y1;
    for (int o = 32; o; o >>= 1) { s1 += __shfl_down(s1, o); s2 += __shfl_down(s2, o); }
    __shared__ float a1[4], a2[4], mv[2];
    if ((t & 63) == 0) { a1[t >> 6] = s1; a2[t >> 6] = s2; }
    __syncthreads();
    if (t == 0) {
        float S1 = a1[0] + a1[1] + a1[2] + a1[3];
        float S2 = a2[0] + a2[1] + a2[2] + a2[3];
        float mu = S1 / 512.f;
        mv[0] = mu;
        mv[1] = rsqrtf(S2 / 512.f - mu * mu + 1e-5f);
    }
    __syncthreads();
    int e = pair_e[p];
    const float* ge = g + e * HID_DIM;
    const float* be = bb + e * HID_DIM;
    float mu = mv[0], ir = mv[1];
    float n0 = (y0 - mu) * ir * ge[t] + be[t];
    float n1 = (y1 - mu) * ir * ge[t + 256] + be[t + 256];
    unsigned short* orow = hidb + (size_t)p * HID_DIM;
    orow[t]       = f2bf(0.5f * n0 * (1.f + erff(n0 * 0.70710678118654752f)));
    orow[t + 256] = f2bf(0.5f * n1 * (1.f + erff(n1 * 0.70710678118654752f)));
}

// ---------------- bf16 MFMA grouped GEMM, 128x128x32 tile, 4 waves
// A: bf16 row-major [rows][lda], row = (list? list[r] : r) >> rowshift, +acol0
// W: permuted bf16 [K/8][N][8] per expert
// MODE 0: Cf[p*ldc+col]=acc+bias  MODE 1: Cb=bf16(...)  MODE 2: atomic out
template<int MODE, bool SPLIT>
__global__ __launch_bounds__(256)
void k_mm(const unsigned short* __restrict__ A, const unsigned short* __restrict__ Alo,
          int lda, int rowshift, int acol0,
          const unsigned short* __restrict__ Wp, const unsigned short* __restrict__ Wlo,
          size_t wstride,
          const float* __restrict__ bias, int bstride,
          float* __restrict__ Cf, unsigned short* __restrict__ Cb, int ldc,
          const int* __restrict__ lists, const int* __restrict__ counts, int Mfix,
          int N, int Kdim,
          float* __restrict__ outp, const float* __restrict__ pw, int actType) {
    const int e = blockIdx.z;
    const int cnt = counts ? counts[e] : Mfix;
    const int m0 = blockIdx.y * 128;
    if (m0 >= cnt) return;
    const int n0 = blockIdx.x * 128;
    const unsigned short* W = Wp + (size_t)e * wstride;
    const unsigned short* Wl = SPLIT ? (Wlo + (size_t)e * wstride) : nullptr;
    const int* list = lists ? (lists + e * B_TOK) : nullptr;

    __shared__ unsigned short Alds[SPLIT ? 8192 : 4096];  // [kg=4][128][8] (+lo)
    __shared__ unsigned short Blds[SPLIT ? 8192 : 4096];

    const int tid  = threadIdx.x;
    const int lane = tid & 63;
    const int wid  = tid >> 6;
    const int c0 = wid * 64 + lane;   // chunk 0..255
    const int c1 = c0 + 256;          // chunk 256..511

    // A-chunk global sources (chunk -> kg = c>>7, rowlocal = c&127)
    size_t aoff0, aoff1;
    {
        int r = m0 + (c0 & 127);
        int p = (r < cnt) ? (list ? list[r] : r) : 0;
        aoff0 = (size_t)(p >> rowshift) * lda + acol0 + (c0 >> 7) * 8;
        r = m0 + (c1 & 127);
        p = (r < cnt) ? (list ? list[r] : r) : 0;
        aoff1 = (size_t)(p >> rowshift) * lda + acol0 + (c1 >> 7) * 8;
    }
    const unsigned short* a0 = A + aoff0;
    const unsigned short* a1 = A + aoff1;
    const unsigned short* al0 = SPLIT ? (Alo + aoff0) : nullptr;
    const unsigned short* al1 = SPLIT ? (Alo + aoff1) : nullptr;
    const unsigned short* b0 = W + ((size_t)(c0 >> 7) * N + n0 + (c0 & 127)) * 8;
    const unsigned short* b1 = W + ((size_t)(c1 >> 7) * N + n0 + (c1 & 127)) * 8;
    const unsigned short* bl0 = SPLIT ? (Wl + ((size_t)(c0 >> 7) * N + n0 + (c0 & 127)) * 8) : nullptr;
    const unsigned short* bl1 = SPLIT ? (Wl + ((size_t)(c1 >> 7) * N + n0 + (c1 & 127)) * 8) : nullptr;

    unsigned short* Ab0 = &Alds[(wid * 64) * 8];
    unsigned short* Ab1 = &Alds[(256 + wid * 64) * 8];
    unsigned short* Bb0 = &Blds[(wid * 64) * 8];
    unsigned short* Bb1 = &Blds[(256 + wid * 64) * 8];

    const int wm = wid >> 1, wn = wid & 1;
    const int lr = lane & 15, lg = lane >> 4;

    f32x4 acc[4][4];
#pragma unroll
    for (int i = 0; i < 4; ++i)
#pragma unroll
        for (int j = 0; j < 4; ++j) acc[i][j] = (f32x4){0.f, 0.f, 0.f, 0.f};

    const size_t bstep = (size_t)32 * N;
    for (int k0 = 0; k0 < Kdim; k0 += 32) {
        glds16(a0, Ab0); glds16(a1, Ab1);
        glds16(b0, Bb0); glds16(b1, Bb1);
        if constexpr (SPLIT) {
            glds16(al0, &Alds[4096 + (wid * 64) * 8]);
            glds16(al1, &Alds[4096 + (256 + wid * 64) * 8]);
            glds16(bl0, &Blds[4096 + (wid * 64) * 8]);
            glds16(bl1, &Blds[4096 + (256 + wid * 64) * 8]);
            al0 += 32; al1 += 32; bl0 += bstep; bl1 += bstep;
        }
        a0 += 32; a1 += 32; b0 += bstep; b1 += bstep;
        __syncthreads();   // drains vmcnt(0) -> LDS tiles ready

        bf16x8 af[4], bfr[4];
#pragma unroll
        for (int i = 0; i < 4; ++i)
            af[i] = *(const bf16x8*)&Alds[((lg << 7) + wm * 64 + i * 16 + lr) * 8];
#pragma unroll
        for (int i = 0; i < 4; ++i)
            bfr[i] = *(const bf16x8*)&Blds[((lg << 7) + wn * 64 + i * 16 + lr) * 8];
#pragma unroll
        for (int mi = 0; mi < 4; ++mi)
#pragma unroll
            for (int ni = 0; ni < 4; ++ni)
                acc[mi][ni] = __builtin_amdgcn_mfma_f32_16x16x32_bf16(af[mi], bfr[ni], acc[mi][ni], 0, 0, 0);
        if constexpr (SPLIT) {
            bf16x8 afl[4], bfl[4];
#pragma unroll
            for (int i = 0; i < 4; ++i)
                afl[i] = *(const bf16x8*)&Alds[4096 + ((lg << 7) + wm * 64 + i * 16 + lr) * 8];
#pragma unroll
            for (int i = 0; i < 4; ++i)
                bfl[i] = *(const bf16x8*)&Blds[4096 + ((lg << 7) + wn * 64 + i * 16 + lr) * 8];
#pragma unroll
            for (int mi = 0; mi < 4; ++mi)
#pragma unroll
                for (int ni = 0; ni < 4; ++ni) {
                    acc[mi][ni] = __builtin_amdgcn_mfma_f32_16x16x32_bf16(af[mi],  bfl[ni], acc[mi][ni], 0, 0, 0);
                    acc[mi][ni] = __builtin_amdgcn_mfma_f32_16x16x32_bf16(afl[mi], bfr[ni], acc[mi][ni], 0, 0, 0);
                }
        }
        __syncthreads();
    }

    // epilogue: C/D layout col = lane&15, row = (lane>>4)*4 + reg  [m89-verified]
    float bv[4];
#pragma unroll
    for (int ni = 0; ni < 4; ++ni)
        bv[ni] = bias[(size_t)e * bstride + n0 + wn * 64 + ni * 16 + lr];

#pragma unroll
    for (int mi = 0; mi < 4; ++mi) {
        int rbase = m0 + wm * 64 + mi * 16 + lg * 4;
#pragma unroll
        for (int rg = 0; rg < 4; ++rg) {
            int r = rbase + rg;
            if (r >= cnt) continue;
            int p = list ? list[r] : r;
#pragma unroll
            for (int ni = 0; ni < 4; ++ni) {
                int col = n0 + wn * 64 + ni * 16 + lr;
                float v = acc[mi][ni][rg] + bv[ni];
                if (MODE == 0) {
                    Cf[(size_t)p * ldc + col] = v;
                } else if (MODE == 1) {
                    Cb[(size_t)p * ldc + col] = f2bf(v);
                } else {
                    int token = p >> 1;
                    atomicAdd(outp + (size_t)token * D_DIM + col, pw[p] * apply_act(v, actType));
                }
            }
        }
    }
}

extern "C" void kernel_launch(void* const* d_in, const int* in_sizes, int n_in,
                              void* d_out, int out_size, void* d_ws, size_t ws_size,
                              hipStream_t stream) {
    const float* h         = (const float*)d_in[0];
    const float* x         = (const float*)d_in[1];
    const int*   lidx      = (const int*)d_in[2];
    const float* layer_emb = (const float*)d_in[3];
    const float* phase_emb = (const float*)d_in[4];
    const float* Wr1       = (const float*)d_in[5];
    const float* br1       = (const float*)d_in[6];
    const float* lnr_g     = (const float*)d_in[7];
    const float* lnr_b     = (const float*)d_in[8];
    const float* Wr2       = (const float*)d_in[9];
    const float* br2       = (const float*)d_in[10];
    const float* W1        = (const float*)d_in[11];
    const float* b1        = (const float*)d_in[12];
    const float* ln1g      = (const float*)d_in[13];
    const float* ln1b      = (const float*)d_in[14];
    const float* W2        = (const float*)d_in[15];
    const float* b2        = (const float*)d_in[16];
    const float* Wa        = (const float*)d_in[17];
    const float* ba        = (const float*)d_in[18];
    const float* Wb_       = (const float*)d_in[19];
    const float* bbv       = (const float*)d_in[20];
    const float* Wg        = (const float*)d_in[21];
    const float* bg        = (const float*)d_in[22];
    const float* Wv        = (const float*)d_in[23];
    const float* bv        = (const float*)d_in[24];
    float* out = (float*)d_out;

    char* ws = (char*)d_ws;
    size_t off = 0;
    auto alloc = [&](size_t nb) { void* p = ws + off; off = (off + nb + 255) & ~(size_t)255; return p; };
    float*          rconstp = (float*)alloc(RH_DIM * 4);
    int*            pair_e  = (int*)alloc(NPAIR * 4);
    float*          pair_w  = (float*)alloc(NPAIR * 4);
    int*            counts  = (int*)alloc(64);
    int*            lists   = (int*)alloc((size_t)E_NUM * B_TOK * 4);
    unsigned short* hx_hi   = (unsigned short*)alloc((size_t)B_TOK * 2048 * 2);   // 16 MB
    unsigned short* hid_bf  = (unsigned short*)alloc((size_t)NPAIR * 512 * 2);    // 8 MB
    unsigned short* wsc_hi  = (unsigned short*)alloc((size_t)8 * 512 * 4096 * 2); // 33.6 MB (max = W2)
    unsigned short* wsc_lo  = (unsigned short*)alloc((size_t)2048 * 256 * 2);     // 1 MB (Wr1 lo)
    char*           featsR  = (char*)alloc((size_t)NPAIR * 4096 * 2);             // 67 MB
    // aliases inside featsR (lifetimes disjoint from feats itself):
    float*          rpre    = (float*)featsR;                                // 4 MB, dead after k_route
    float*          hidf    = (float*)(featsR + ((size_t)4 << 20));          // 16 MB, dead after k_lngelu
    unsigned short* hx_lo   = (unsigned short*)(featsR + ((size_t)20 << 20));// 16 MB, dead after routing GEMM
    unsigned short* feats   = (unsigned short*)featsR;                       // written by layer2

    (void)hipMemsetAsync(d_out, 0, (size_t)out_size * 4, stream);
    (void)hipMemsetAsync(counts, 0, 64, stream);

    // ---- precision-critical routing path (split bf16 ~ fp32 accuracy)
    k_hxbf<<<4096, 256, 0, stream>>>(h, x, hx_hi, hx_lo);
    k_convW<true><<<dim3(1, 256, 1), 256, 0, stream>>>(Wr1, wsc_hi, wsc_lo, 2048, RH_DIM);
    k_rconst<<<1, 256, 0, stream>>>(layer_emb, phase_emb, lidx, Wr1, br1, rconstp);
    k_mm<0, true><<<dim3(2, 32, 1), 256, 0, stream>>>(
        hx_hi, hx_lo, 2048, 0, 0, wsc_hi, wsc_lo, 0, rconstp, 0,
        rpre, nullptr, RH_DIM, nullptr, nullptr, B_TOK, RH_DIM, 2048,
        nullptr, nullptr, 0);
    k_route<<<B_TOK, 256, 0, stream>>>(rpre, lnr_g, lnr_b, Wr2, br2,
                                       pair_e, pair_w, lists, counts);

    // ---- layer1: hid[p](512) = hx[token] @ W1[e] + b1[e]
    k_convW<false><<<dim3(2, 256, 8), 256, 0, stream>>>(W1, wsc_hi, nullptr, 2048, HID_DIM);
    k_mm<0, false><<<dim3(4, 32, 8), 256, 0, stream>>>(
        hx_hi, nullptr, 2048, 1, 0, wsc_hi, nullptr, (size_t)2048 * HID_DIM, b1, HID_DIM,
        hidf, nullptr, HID_DIM, lists, counts, 0, HID_DIM, 2048,
        nullptr, nullptr, 0);
    k_lngelu<<<NPAIR, 256, 0, stream>>>(hidf, hid_bf, pair_e, ln1g, ln1b);

    // ---- layer2: feats[p](4096) = hid_bf[p] @ W2[e] + b2[e]  (bf16 out)
    k_convW<false><<<dim3(16, 64, 8), 256, 0, stream>>>(W2, wsc_hi, nullptr, HID_DIM, 4096);
    k_mm<1, false><<<dim3(32, 32, 8), 256, 0, stream>>>(
        hid_bf, nullptr, 512, 0, 0, wsc_hi, nullptr, (size_t)HID_DIM * 4096, b2, 4096,
        nullptr, feats, 4096, lists, counts, 0, 4096, HID_DIM,
        nullptr, nullptr, 0);

    // ---- layer3 x4: out[o][token] += w * act(feats[p][o*1024:+1024] @ W[e] + b[e])
    const float* Ws[4] = {Wa, Wb_, Wg, Wv};
    const float* bs[4] = {ba, bbv, bg, bv};
    for (int o = 0; o < 4; ++o) {
        k_convW<false><<<dim3(4, 128, 8), 256, 0, stream>>>(Ws[o], wsc_hi, nullptr, D_DIM, D_DIM);
        k_mm<2, false><<<dim3(8, 32, 8), 256, 0, stream>>>(
            feats, nullptr, 4096, 0, o * D_DIM, wsc_hi, nullptr, (size_t)D_DIM * D_DIM,
            bs[o], D_DIM, nullptr, nullptr, 0, lists, counts, 0, D_DIM, D_DIM,
            out + (size_t)o * B_TOK * D_DIM, pair_w, o);
    }
}

// Round 3
// 732.437 us; speedup vs baseline: 3.3193x; 1.0525x over previous
//
#include <hip/hip_runtime.h>
#include <hip/hip_bf16.h>

#define B_TOK   4096
#define D_DIM   1024
#define E_NUM   8
#define HID_DIM 512
#define RH_DIM  256
#define EMB_DIM 32
#define NPAIR   (B_TOK * 2)   // 8192

typedef __attribute__((ext_vector_type(8))) short    bf16x8;
typedef __attribute__((ext_vector_type(8))) unsigned short u16x8;
typedef __attribute__((ext_vector_type(4))) float    f32x4;

__device__ __forceinline__ unsigned short f2bf(float f) {
    union { float f; unsigned u; } v; v.f = f;
    unsigned r = (v.u + 0x7fffu + ((v.u >> 16) & 1u)) >> 16;
    return (unsigned short)r;
}
__device__ __forceinline__ float bf2f(unsigned short b) {
    union { unsigned u; float f; } v; v.u = ((unsigned)b) << 16;
    return v.f;
}

__device__ __forceinline__ void glds16(const void* g, void* l) {
    __builtin_amdgcn_global_load_lds(
        (const __attribute__((address_space(1))) unsigned int*)g,
        (__attribute__((address_space(3))) unsigned int*)l, 16, 0, 0);
}

__device__ inline float apply_act(float v, int a) {
    if (a == 0 || a == 2) return 1.f / (1.f + expf(-v));        // sigmoid
    if (a == 1) return fmaxf(v, 0.f) + log1pf(expf(-fabsf(v))); // softplus
    return v;                                                    // identity
}

// ---------------- hx -> bf16 (hi + lo split), layout [token][2048]
__global__ void k_hxbf(const float* __restrict__ h, const float* __restrict__ x,
                       unsigned short* __restrict__ hi, unsigned short* __restrict__ lo) {
    int gid = blockIdx.x * 256 + threadIdx.x;
    int token = gid >> 8;
    int c0 = (gid & 255) * 8;
    const float* src = (c0 < 1024) ? (h + (size_t)token * 1024 + c0)
                                   : (x + (size_t)token * 1024 + c0 - 1024);
    u16x8 oh, ol;
#pragma unroll
    for (int j = 0; j < 8; ++j) {
        float f = src[j];
        unsigned short hb = f2bf(f);
        oh[j] = hb;
        ol[j] = f2bf(f - bf2f(hb));
    }
    size_t o = (size_t)gid * 8;
    *(u16x8*)(hi + o) = oh;
    *(u16x8*)(lo + o) = ol;
}

// ---------------- W [K][N] fp32 -> permuted bf16 [K/8][N][8]; z = matrix*eper + e
template<bool SPLIT>
__global__ void k_convW(const float* __restrict__ in0, const float* __restrict__ in1,
                        unsigned short* __restrict__ oh, unsigned short* __restrict__ ol,
                        int K, int N, int eper) {
    int z = blockIdx.z;
    int e = z % eper, m = z / eper;
    const float* in = (m ? in1 : in0) + (size_t)e * K * N;
    int n  = blockIdx.x * 256 + threadIdx.x;
    int kg = blockIdx.y;
    const float* ip = in + (size_t)kg * 8 * N + n;
    u16x8 hv, lv;
#pragma unroll
    for (int j = 0; j < 8; ++j) {
        float f = ip[(size_t)j * N];
        unsigned short hb = f2bf(f);
        hv[j] = hb;
        if (SPLIT) lv[j] = f2bf(f - bf2f(hb));
    }
    size_t o = (size_t)z * K * N + ((size_t)kg * N + n) * 8;
    *(u16x8*)(oh + o) = hv;
    if (SPLIT) *(u16x8*)(ol + o) = lv;
}

// ---------------- routing const: br1 + le@Wr1[2048:2080] + pe@Wr1[2080:2112]
__global__ void k_rconst(const float* __restrict__ layer_emb,
                         const float* __restrict__ phase_emb,
                         const int* __restrict__ lidx,
                         const float* __restrict__ Wr1,
                         const float* __restrict__ br1,
                         float* __restrict__ rconst) {
    int j = threadIdx.x;
    int li = lidx[0];
    float acc = br1[j];
    for (int t = 0; t < EMB_DIM; ++t)
        acc += layer_emb[li * EMB_DIM + t] * Wr1[(2048 + t) * RH_DIM + j];
    for (int t = 0; t < EMB_DIM; ++t)
        acc += phase_emb[t] * Wr1[(2080 + t) * RH_DIM + j];
    rconst[j] = acc;
}

// ---------------- routing tail: LN + gelu + logits(parallel) + top2 + lists
__global__ void k_route(const float* __restrict__ rpre,
                        const float* __restrict__ lnr_g, const float* __restrict__ lnr_b,
                        const float* __restrict__ Wr2, const float* __restrict__ br2,
                        int* __restrict__ pair_e, float* __restrict__ pair_w,
                        int* __restrict__ lists, int* __restrict__ counts) {
    int b = blockIdx.x, t = threadIdx.x;
    __shared__ float sv[RH_DIM];
    __shared__ float a1[4], a2[4], mv[2];
    __shared__ float wsum[4][E_NUM];
    __shared__ float lg[E_NUM];

    float y = rpre[(size_t)b * RH_DIM + t];
    float s1 = y, s2 = y * y;
    for (int o = 32; o; o >>= 1) { s1 += __shfl_down(s1, o); s2 += __shfl_down(s2, o); }
    if ((t & 63) == 0) { a1[t >> 6] = s1; a2[t >> 6] = s2; }
    __syncthreads();
    if (t == 0) {
        float S1 = a1[0] + a1[1] + a1[2] + a1[3];
        float S2 = a2[0] + a2[1] + a2[2] + a2[3];
        float mu = S1 / 256.f;
        mv[0] = mu;
        mv[1] = rsqrtf(S2 / 256.f - mu * mu + 1e-5f);
    }
    __syncthreads();
    float n = (y - mv[0]) * mv[1] * lnr_g[t] + lnr_b[t];
    sv[t] = 0.5f * n * (1.f + erff(n * 0.70710678118654752f));
    __syncthreads();

    // logits: all 256 threads. e = t&7, chunk c = t>>3 (8 MACs each)
    {
        int e = t & 7, c = t >> 3;
        float part = 0.f;
#pragma unroll
        for (int jj = 0; jj < 8; ++jj)
            part += sv[c * 8 + jj] * Wr2[(c * 8 + jj) * E_NUM + e];
        part += __shfl_down(part, 8);
        part += __shfl_down(part, 16);
        part += __shfl_down(part, 32);
        if ((t & 63) < 8) wsum[t >> 6][e] = part;
    }
    __syncthreads();
    if (t < E_NUM)
        lg[t] = br2[t] + wsum[0][t] + wsum[1][t] + wsum[2][t] + wsum[3][t];
    __syncthreads();
    if (t == 0) {
        float v0 = -1e30f; int i0 = 0;
        for (int e = 0; e < E_NUM; ++e) if (lg[e] > v0) { v0 = lg[e]; i0 = e; }
        float v1 = -1e30f; int i1 = 0;
        for (int e = 0; e < E_NUM; ++e) if (e != i0 && lg[e] > v1) { v1 = lg[e]; i1 = e; }
        float e1 = expf(v1 - v0);
        pair_e[2 * b] = i0;  pair_e[2 * b + 1] = i1;
        pair_w[2 * b] = 1.f / (1.f + e1);
        pair_w[2 * b + 1] = e1 / (1.f + e1);
        int p0 = atomicAdd(&counts[i0], 1); lists[i0 * B_TOK + p0] = 2 * b;
        int p1 = atomicAdd(&counts[i1], 1); lists[i1 * B_TOK + p1] = 2 * b + 1;
    }
}

// ---------------- LN + gelu over hid rows (512), fp32 in -> bf16 out
__global__ void k_lngelu(const float* __restrict__ hid, unsigned short* __restrict__ hidb,
                         const int* __restrict__ pair_e,
                         const float* __restrict__ g, const float* __restrict__ bb) {
    int p = blockIdx.x, t = threadIdx.x;
    const float* row = hid + (size_t)p * HID_DIM;
    float y0 = row[t], y1 = row[t + 256];
    float s1 = y0 + y1, s2 = y0 * y0 + y1 * y1;
    for (int o = 32; o; o >>= 1) { s1 += __shfl_down(s1, o); s2 += __shfl_down(s2, o); }
    __shared__ float a1[4], a2[4], mv[2];
    if ((t & 63) == 0) { a1[t >> 6] = s1; a2[t >> 6] = s2; }
    __syncthreads();
    if (t == 0) {
        float S1 = a1[0] + a1[1] + a1[2] + a1[3];
        float S2 = a2[0] + a2[1] + a2[2] + a2[3];
        float mu = S1 / 512.f;
        mv[0] = mu;
        mv[1] = rsqrtf(S2 / 512.f - mu * mu + 1e-5f);
    }
    __syncthreads();
    int e = pair_e[p];
    const float* ge = g + e * HID_DIM;
    const float* be = bb + e * HID_DIM;
    float mu = mv[0], ir = mv[1];
    float n0 = (y0 - mu) * ir * ge[t] + be[t];
    float n1 = (y1 - mu) * ir * ge[t + 256] + be[t + 256];
    unsigned short* orow = hidb + (size_t)p * HID_DIM;
    orow[t]       = f2bf(0.5f * n0 * (1.f + erff(n0 * 0.70710678118654752f)));
    orow[t + 256] = f2bf(0.5f * n1 * (1.f + erff(n1 * 0.70710678118654752f)));
}

// ---------------- bf16 MFMA grouped GEMM, 128x128x32 tile, 4 waves
// MODE 0: Cf=acc+bias   MODE 1: Cb=bf16(acc+bias)
// MODE 2: atomic out += pw*act(acc+bias), z = o-major (o=obase+z/8, e=z%8)
// MODE 3: atomicAdd Cf += acc (+bias iff kh==0), z = kh-major (e=z%nz_e, kh=z/nz_e)
template<int MODE, bool SPLIT>
__global__ __launch_bounds__(256)
void k_mm(const unsigned short* __restrict__ A, const unsigned short* __restrict__ Alo,
          int lda, int rowshift, int acol0,
          const unsigned short* __restrict__ Wp, const unsigned short* __restrict__ Wlo,
          size_t wstride,
          const float* __restrict__ bias, int bstride,
          float* __restrict__ Cf, unsigned short* __restrict__ Cb, int ldc,
          const int* __restrict__ lists, const int* __restrict__ counts, int Mfix,
          int N, int Kdim, int nz_e, int obase,
          float* __restrict__ outp, const float* __restrict__ pw) {
    const int z  = blockIdx.z;
    const int e  = z % nz_e;
    const int zq = z / nz_e;
    const int kh = (MODE == 3) ? zq : 0;
    const int o  = (MODE == 2) ? (obase + zq) : 0;
    const int cnt = counts ? counts[e] : Mfix;
    const int m0 = blockIdx.y * 128;
    if (m0 >= cnt) return;
    const int n0 = blockIdx.x * 128;

    const size_t woff = (MODE == 2) ? (size_t)z * wstride
                                    : ((size_t)e * wstride + (size_t)kh * Kdim * N);
    const unsigned short* W  = Wp + woff;
    const unsigned short* Wl = SPLIT ? (Wlo + woff) : nullptr;
    const float* bptr = bias + (MODE == 2 ? (size_t)(o * E_NUM + e) * bstride
                                          : (size_t)e * bstride);
    const int acol = acol0 + (MODE == 2 ? o * D_DIM : kh * Kdim);
    const int* list = lists ? (lists + e * B_TOK) : nullptr;

    __shared__ unsigned short Alds[SPLIT ? 8192 : 4096];  // [kg=4][128][8] (+lo)
    __shared__ unsigned short Blds[SPLIT ? 8192 : 4096];

    const int tid  = threadIdx.x;
    const int lane = tid & 63;
    const int wid  = tid >> 6;
    const int c0 = wid * 64 + lane;
    const int c1 = c0 + 256;

    size_t aoff0, aoff1;
    {
        int r = m0 + (c0 & 127);
        int p = (r < cnt) ? (list ? list[r] : r) : 0;
        aoff0 = (size_t)(p >> rowshift) * lda + acol + (c0 >> 7) * 8;
        r = m0 + (c1 & 127);
        p = (r < cnt) ? (list ? list[r] : r) : 0;
        aoff1 = (size_t)(p >> rowshift) * lda + acol + (c1 >> 7) * 8;
    }
    const unsigned short* a0 = A + aoff0;
    const unsigned short* a1 = A + aoff1;
    const unsigned short* al0 = SPLIT ? (Alo + aoff0) : nullptr;
    const unsigned short* al1 = SPLIT ? (Alo + aoff1) : nullptr;
    const unsigned short* b0 = W + ((size_t)(c0 >> 7) * N + n0 + (c0 & 127)) * 8;
    const unsigned short* b1 = W + ((size_t)(c1 >> 7) * N + n0 + (c1 & 127)) * 8;
    const unsigned short* bl0 = SPLIT ? (Wl + ((size_t)(c0 >> 7) * N + n0 + (c0 & 127)) * 8) : nullptr;
    const unsigned short* bl1 = SPLIT ? (Wl + ((size_t)(c1 >> 7) * N + n0 + (c1 & 127)) * 8) : nullptr;

    unsigned short* Ab0 = &Alds[(wid * 64) * 8];
    unsigned short* Ab1 = &Alds[(256 + wid * 64) * 8];
    unsigned short* Bb0 = &Blds[(wid * 64) * 8];
    unsigned short* Bb1 = &Blds[(256 + wid * 64) * 8];

    const int wm = wid >> 1, wn = wid & 1;
    const int lr = lane & 15, lg = lane >> 4;

    f32x4 acc[4][4];
#pragma unroll
    for (int i = 0; i < 4; ++i)
#pragma unroll
        for (int j = 0; j < 4; ++j) acc[i][j] = (f32x4){0.f, 0.f, 0.f, 0.f};

    const size_t bstep = (size_t)32 * N;
    for (int k0 = 0; k0 < Kdim; k0 += 32) {
        glds16(a0, Ab0); glds16(a1, Ab1);
        glds16(b0, Bb0); glds16(b1, Bb1);
        if constexpr (SPLIT) {
            glds16(al0, &Alds[4096 + (wid * 64) * 8]);
            glds16(al1, &Alds[4096 + (256 + wid * 64) * 8]);
            glds16(bl0, &Blds[4096 + (wid * 64) * 8]);
            glds16(bl1, &Blds[4096 + (256 + wid * 64) * 8]);
            al0 += 32; al1 += 32; bl0 += bstep; bl1 += bstep;
        }
        a0 += 32; a1 += 32; b0 += bstep; b1 += bstep;
        __syncthreads();

        bf16x8 af[4], bfr[4];
#pragma unroll
        for (int i = 0; i < 4; ++i)
            af[i] = *(const bf16x8*)&Alds[((lg << 7) + wm * 64 + i * 16 + lr) * 8];
#pragma unroll
        for (int i = 0; i < 4; ++i)
            bfr[i] = *(const bf16x8*)&Blds[((lg << 7) + wn * 64 + i * 16 + lr) * 8];
#pragma unroll
        for (int mi = 0; mi < 4; ++mi)
#pragma unroll
            for (int ni = 0; ni < 4; ++ni)
                acc[mi][ni] = __builtin_amdgcn_mfma_f32_16x16x32_bf16(af[mi], bfr[ni], acc[mi][ni], 0, 0, 0);
        if constexpr (SPLIT) {
            bf16x8 afl[4], bfl[4];
#pragma unroll
            for (int i = 0; i < 4; ++i)
                afl[i] = *(const bf16x8*)&Alds[4096 + ((lg << 7) + wm * 64 + i * 16 + lr) * 8];
#pragma unroll
            for (int i = 0; i < 4; ++i)
                bfl[i] = *(const bf16x8*)&Blds[4096 + ((lg << 7) + wn * 64 + i * 16 + lr) * 8];
#pragma unroll
            for (int mi = 0; mi < 4; ++mi)
#pragma unroll
                for (int ni = 0; ni < 4; ++ni) {
                    acc[mi][ni] = __builtin_amdgcn_mfma_f32_16x16x32_bf16(af[mi],  bfl[ni], acc[mi][ni], 0, 0, 0);
                    acc[mi][ni] = __builtin_amdgcn_mfma_f32_16x16x32_bf16(afl[mi], bfr[ni], acc[mi][ni], 0, 0, 0);
                }
        }
        __syncthreads();
    }

    float bv[4];
#pragma unroll
    for (int ni = 0; ni < 4; ++ni)
        bv[ni] = (MODE != 3 || kh == 0) ? bptr[n0 + wn * 64 + ni * 16 + lr] : 0.f;

#pragma unroll
    for (int mi = 0; mi < 4; ++mi) {
        int rbase = m0 + wm * 64 + mi * 16 + lg * 4;
#pragma unroll
        for (int rg = 0; rg < 4; ++rg) {
            int r = rbase + rg;
            if (r >= cnt) continue;
            int p = list ? list[r] : r;
#pragma unroll
            for (int ni = 0; ni < 4; ++ni) {
                int col = n0 + wn * 64 + ni * 16 + lr;
                float v = acc[mi][ni][rg] + bv[ni];
                if (MODE == 0) {
                    Cf[(size_t)p * ldc + col] = v;
                } else if (MODE == 1) {
                    Cb[(size_t)p * ldc + col] = f2bf(v);
                } else if (MODE == 3) {
                    atomicAdd(Cf + (size_t)p * ldc + col, v);
                } else {
                    int token = p >> 1;
                    atomicAdd(outp + (size_t)o * B_TOK * D_DIM + (size_t)token * D_DIM + col,
                              pw[p] * apply_act(v, o));
                }
            }
        }
    }
}

extern "C" void kernel_launch(void* const* d_in, const int* in_sizes, int n_in,
                              void* d_out, int out_size, void* d_ws, size_t ws_size,
                              hipStream_t stream) {
    const float* h         = (const float*)d_in[0];
    const float* x         = (const float*)d_in[1];
    const int*   lidx      = (const int*)d_in[2];
    const float* layer_emb = (const float*)d_in[3];
    const float* phase_emb = (const float*)d_in[4];
    const float* Wr1       = (const float*)d_in[5];
    const float* br1       = (const float*)d_in[6];
    const float* lnr_g     = (const float*)d_in[7];
    const float* lnr_b     = (const float*)d_in[8];
    const float* Wr2       = (const float*)d_in[9];
    const float* br2       = (const float*)d_in[10];
    const float* W1        = (const float*)d_in[11];
    const float* b1        = (const float*)d_in[12];
    const float* ln1g      = (const float*)d_in[13];
    const float* ln1b      = (const float*)d_in[14];
    const float* W2        = (const float*)d_in[15];
    const float* b2        = (const float*)d_in[16];
    const float* Wa        = (const float*)d_in[17];
    const float* ba        = (const float*)d_in[18];
    const float* Wb_       = (const float*)d_in[19];
    const float* bbv       = (const float*)d_in[20];
    const float* Wg        = (const float*)d_in[21];
    const float* bg        = (const float*)d_in[22];
    const float* Wv        = (const float*)d_in[23];
    const float* bv        = (const float*)d_in[24];
    float* out = (float*)d_out;

    char* ws = (char*)d_ws;
    size_t off = 0;
    auto alloc = [&](size_t nb) { void* p = ws + off; off = (off + nb + 255) & ~(size_t)255; return p; };
    float*          rconstp = (float*)alloc(RH_DIM * 4);
    int*            pair_e  = (int*)alloc(NPAIR * 4);
    float*          pair_w  = (float*)alloc(NPAIR * 4);
    int*            counts  = (int*)alloc(64);
    int*            lists   = (int*)alloc((size_t)E_NUM * B_TOK * 4);
    float*          bcat    = (float*)alloc((size_t)4 * E_NUM * D_DIM * 4);       // 128 KB
    unsigned short* hx_hi   = (unsigned short*)alloc((size_t)B_TOK * 2048 * 2);   // 16.8 MB
    unsigned short* hid_bf  = (unsigned short*)alloc((size_t)NPAIR * 512 * 2);    // 8.4 MB
    unsigned short* wsc_hi  = (unsigned short*)alloc((size_t)8 * 512 * 4096 * 2); // 33.6 MB
    unsigned short* wsc_lo  = (unsigned short*)alloc((size_t)2048 * 256 * 2);     // 1 MB
    char*           featsR  = (char*)alloc((size_t)NPAIR * 4096 * 2);             // 67.1 MB
    // aliases inside featsR (disjoint lifetimes):
    float*          rpre    = (float*)featsR;                                 // [0,4.2MB)   dead after k_route
    float*          hidf    = (float*)(featsR + ((size_t)5 << 20));           // [5,21.8MB)  dead after k_lngelu
    unsigned short* hx_lo   = (unsigned short*)(featsR + ((size_t)22 << 20)); // [22,38.8MB) dead after routing mm
    unsigned short* feats   = (unsigned short*)featsR;                        // layer2 output

    (void)hipMemsetAsync(d_out, 0, (size_t)out_size * 4, stream);
    (void)hipMemsetAsync(counts, 0, 64, stream);
    (void)hipMemsetAsync(hidf, 0, (size_t)NPAIR * HID_DIM * 4, stream);  // MODE3 accum
    // stage layer3 biases contiguous: bcat[o][e][1024]
    (void)hipMemcpyAsync(bcat + 0 * E_NUM * D_DIM, ba,  (size_t)E_NUM * D_DIM * 4, hipMemcpyDeviceToDevice, stream);
    (void)hipMemcpyAsync(bcat + 1 * E_NUM * D_DIM, bbv, (size_t)E_NUM * D_DIM * 4, hipMemcpyDeviceToDevice, stream);
    (void)hipMemcpyAsync(bcat + 2 * E_NUM * D_DIM, bg,  (size_t)E_NUM * D_DIM * 4, hipMemcpyDeviceToDevice, stream);
    (void)hipMemcpyAsync(bcat + 3 * E_NUM * D_DIM, bv,  (size_t)E_NUM * D_DIM * 4, hipMemcpyDeviceToDevice, stream);

    // ---- routing path (split bf16 ~ fp32 accuracy)
    k_hxbf<<<4096, 256, 0, stream>>>(h, x, hx_hi, hx_lo);
    k_convW<true><<<dim3(1, 256, 1), 256, 0, stream>>>(Wr1, nullptr, wsc_hi, wsc_lo, 2048, RH_DIM, 1);
    k_rconst<<<1, 256, 0, stream>>>(layer_emb, phase_emb, lidx, Wr1, br1, rconstp);
    k_mm<0, true><<<dim3(2, 32, 1), 256, 0, stream>>>(
        hx_hi, hx_lo, 2048, 0, 0, wsc_hi, wsc_lo, 0, rconstp, 0,
        rpre, nullptr, RH_DIM, nullptr, nullptr, B_TOK, RH_DIM, 2048, 1, 0,
        nullptr, nullptr);
    k_route<<<B_TOK, 256, 0, stream>>>(rpre, lnr_g, lnr_b, Wr2, br2,
                                       pair_e, pair_w, lists, counts);

    // ---- layer1 (split-K x2): hidf[p](512) += hx[token] @ W1[e] + b1[e]
    k_convW<false><<<dim3(2, 256, 8), 256, 0, stream>>>(W1, nullptr, wsc_hi, nullptr, 2048, HID_DIM, 8);
    k_mm<3, false><<<dim3(4, 32, 16), 256, 0, stream>>>(
        hx_hi, nullptr, 2048, 1, 0, wsc_hi, nullptr, (size_t)2048 * HID_DIM, b1, HID_DIM,
        hidf, nullptr, HID_DIM, lists, counts, 0, HID_DIM, 1024, 8, 0,
        nullptr, nullptr);
    k_lngelu<<<NPAIR, 256, 0, stream>>>(hidf, hid_bf, pair_e, ln1g, ln1b);

    // ---- layer2: feats[p](4096) = hid_bf[p] @ W2[e] + b2[e]  (bf16 out)
    k_convW<false><<<dim3(16, 64, 8), 256, 0, stream>>>(W2, nullptr, wsc_hi, nullptr, HID_DIM, 4096, 8);
    k_mm<1, false><<<dim3(32, 32, 8), 256, 0, stream>>>(
        hid_bf, nullptr, 512, 0, 0, wsc_hi, nullptr, (size_t)HID_DIM * 4096, b2, 4096,
        nullptr, feats, 4096, lists, counts, 0, 4096, HID_DIM, 8, 0,
        nullptr, nullptr);

    // ---- layer3, two fused halves: o in {0,1} then {2,3}
    k_convW<false><<<dim3(4, 128, 16), 256, 0, stream>>>(Wa, Wb_, wsc_hi, nullptr, D_DIM, D_DIM, 8);
    k_mm<2, false><<<dim3(8, 32, 16), 256, 0, stream>>>(
        feats, nullptr, 4096, 0, 0, wsc_hi, nullptr, (size_t)D_DIM * D_DIM, bcat, D_DIM,
        nullptr, nullptr, 0, lists, counts, 0, D_DIM, D_DIM, 8, 0,
        out, pair_w);
    k_convW<false><<<dim3(4, 128, 16), 256, 0, stream>>>(Wg, Wv, wsc_hi, nullptr, D_DIM, D_DIM, 8);
    k_mm<2, false><<<dim3(8, 32, 16), 256, 0, stream>>>(
        feats, nullptr, 4096, 0, 0, wsc_hi, nullptr, (size_t)D_DIM * D_DIM, bcat, D_DIM,
        nullptr, nullptr, 0, lists, counts, 0, D_DIM, D_DIM, 8, 2,
        out, pair_w);
}

// Round 4
// 704.734 us; speedup vs baseline: 3.4498x; 1.0393x over previous
//
#include <hip/hip_runtime.h>
#include <hip/hip_bf16.h>

#define B_TOK   4096
#define D_DIM   1024
#define E_NUM   8
#define HID_DIM 512
#define RH_DIM  256
#define EMB_DIM 32
#define NPAIR   (B_TOK * 2)   // 8192

typedef __attribute__((ext_vector_type(8))) short    bf16x8;
typedef __attribute__((ext_vector_type(8))) unsigned short u16x8;
typedef __attribute__((ext_vector_type(4))) float    f32x4;

__device__ __forceinline__ unsigned short f2bf(float f) {
    union { float f; unsigned u; } v; v.f = f;
    unsigned r = (v.u + 0x7fffu + ((v.u >> 16) & 1u)) >> 16;
    return (unsigned short)r;
}
__device__ __forceinline__ float bf2f(unsigned short b) {
    union { unsigned u; float f; } v; v.u = ((unsigned)b) << 16;
    return v.f;
}

__device__ __forceinline__ void glds16(const void* g, void* l) {
    __builtin_amdgcn_global_load_lds(
        (const __attribute__((address_space(1))) unsigned int*)g,
        (__attribute__((address_space(3))) unsigned int*)l, 16, 0, 0);
}

__device__ inline float apply_act(float v, int a) {
    if (a == 0 || a == 2) return 1.f / (1.f + expf(-v));        // sigmoid
    if (a == 1) return fmaxf(v, 0.f) + log1pf(expf(-fabsf(v))); // softplus
    return v;                                                    // identity
}

// ---------------- hx -> bf16 (hi + lo split), layout [token][2048]
__global__ void k_hxbf(const float* __restrict__ h, const float* __restrict__ x,
                       unsigned short* __restrict__ hi, unsigned short* __restrict__ lo) {
    int gid = blockIdx.x * 256 + threadIdx.x;
    int token = gid >> 8;
    int c0 = (gid & 255) * 8;
    const float* src = (c0 < 1024) ? (h + (size_t)token * 1024 + c0)
                                   : (x + (size_t)token * 1024 + c0 - 1024);
    u16x8 oh, ol;
#pragma unroll
    for (int j = 0; j < 8; ++j) {
        float f = src[j];
        unsigned short hb = f2bf(f);
        oh[j] = hb;
        ol[j] = f2bf(f - bf2f(hb));
    }
    size_t o = (size_t)gid * 8;
    *(u16x8*)(hi + o) = oh;
    *(u16x8*)(lo + o) = ol;
}

// ---------------- W [K][N] fp32 -> permuted bf16 [K/8][N][8]; z = matrix*eper + e
template<bool SPLIT>
__global__ void k_convW(const float* __restrict__ in0, const float* __restrict__ in1,
                        unsigned short* __restrict__ oh, unsigned short* __restrict__ ol,
                        int K, int N, int eper) {
    int z = blockIdx.z;
    int e = z % eper, m = z / eper;
    const float* in = (m ? in1 : in0) + (size_t)e * K * N;
    int n  = blockIdx.x * 256 + threadIdx.x;
    int kg = blockIdx.y;
    const float* ip = in + (size_t)kg * 8 * N + n;
    u16x8 hv, lv;
#pragma unroll
    for (int j = 0; j < 8; ++j) {
        float f = ip[(size_t)j * N];
        unsigned short hb = f2bf(f);
        hv[j] = hb;
        if (SPLIT) lv[j] = f2bf(f - bf2f(hb));
    }
    size_t o = (size_t)z * K * N + ((size_t)kg * N + n) * 8;
    *(u16x8*)(oh + o) = hv;
    if (SPLIT) *(u16x8*)(ol + o) = lv;
}

// ---------------- routing const: br1 + le@Wr1[2048:2080] + pe@Wr1[2080:2112]
__global__ void k_rconst(const float* __restrict__ layer_emb,
                         const float* __restrict__ phase_emb,
                         const int* __restrict__ lidx,
                         const float* __restrict__ Wr1,
                         const float* __restrict__ br1,
                         float* __restrict__ rconst) {
    int j = threadIdx.x;
    int li = lidx[0];
    float acc = br1[j];
    for (int t = 0; t < EMB_DIM; ++t)
        acc += layer_emb[li * EMB_DIM + t] * Wr1[(2048 + t) * RH_DIM + j];
    for (int t = 0; t < EMB_DIM; ++t)
        acc += phase_emb[t] * Wr1[(2080 + t) * RH_DIM + j];
    rconst[j] = acc;
}

// ---------------- routing tail: sum 4 split-K partials (fixed order) + rconst,
// then LN + gelu + logits(parallel) + top2 + lists
__global__ void k_route(const float* __restrict__ Pf, const float* __restrict__ rconst,
                        const float* __restrict__ lnr_g, const float* __restrict__ lnr_b,
                        const float* __restrict__ Wr2, const float* __restrict__ br2,
                        int* __restrict__ pair_e, float* __restrict__ pair_w,
                        int* __restrict__ lists, int* __restrict__ counts) {
    int b = blockIdx.x, t = threadIdx.x;
    __shared__ float sv[RH_DIM];
    __shared__ float a1[4], a2[4], mv[2];
    __shared__ float wsum[4][E_NUM];
    __shared__ float lg[E_NUM];

    size_t idx = (size_t)b * RH_DIM + t;
    const size_t kstride = (size_t)B_TOK * RH_DIM;
    float y = ((Pf[idx] + Pf[idx + kstride]) + (Pf[idx + 2 * kstride] + Pf[idx + 3 * kstride]))
              + rconst[t];
    float s1 = y, s2 = y * y;
    for (int o = 32; o; o >>= 1) { s1 += __shfl_down(s1, o); s2 += __shfl_down(s2, o); }
    if ((t & 63) == 0) { a1[t >> 6] = s1; a2[t >> 6] = s2; }
    __syncthreads();
    if (t == 0) {
        float S1 = a1[0] + a1[1] + a1[2] + a1[3];
        float S2 = a2[0] + a2[1] + a2[2] + a2[3];
        float mu = S1 / 256.f;
        mv[0] = mu;
        mv[1] = rsqrtf(S2 / 256.f - mu * mu + 1e-5f);
    }
    __syncthreads();
    float n = (y - mv[0]) * mv[1] * lnr_g[t] + lnr_b[t];
    sv[t] = 0.5f * n * (1.f + erff(n * 0.70710678118654752f));
    __syncthreads();

    {
        int e = t & 7, c = t >> 3;
        float part = 0.f;
#pragma unroll
        for (int jj = 0; jj < 8; ++jj)
            part += sv[c * 8 + jj] * Wr2[(c * 8 + jj) * E_NUM + e];
        part += __shfl_down(part, 8);
        part += __shfl_down(part, 16);
        part += __shfl_down(part, 32);
        if ((t & 63) < 8) wsum[t >> 6][e] = part;
    }
    __syncthreads();
    if (t < E_NUM)
        lg[t] = br2[t] + wsum[0][t] + wsum[1][t] + wsum[2][t] + wsum[3][t];
    __syncthreads();
    if (t == 0) {
        float v0 = -1e30f; int i0 = 0;
        for (int e = 0; e < E_NUM; ++e) if (lg[e] > v0) { v0 = lg[e]; i0 = e; }
        float v1 = -1e30f; int i1 = 0;
        for (int e = 0; e < E_NUM; ++e) if (e != i0 && lg[e] > v1) { v1 = lg[e]; i1 = e; }
        float e1 = expf(v1 - v0);
        pair_e[2 * b] = i0;  pair_e[2 * b + 1] = i1;
        pair_w[2 * b] = 1.f / (1.f + e1);
        pair_w[2 * b + 1] = e1 / (1.f + e1);
        int p0 = atomicAdd(&counts[i0], 1); lists[i0 * B_TOK + p0] = 2 * b;
        int p1 = atomicAdd(&counts[i1], 1); lists[i1 * B_TOK + p1] = 2 * b + 1;
    }
}

// ---------------- LN + gelu over hid rows (512), fp32 in -> bf16 out
__global__ void k_lngelu(const float* __restrict__ hid, unsigned short* __restrict__ hidb,
                         const int* __restrict__ pair_e,
                         const float* __restrict__ g, const float* __restrict__ bb) {
    int p = blockIdx.x, t = threadIdx.x;
    const float* row = hid + (size_t)p * HID_DIM;
    float y0 = row[t], y1 = row[t + 256];
    float s1 = y0 + y1, s2 = y0 * y0 + y1 * y1;
    for (int o = 32; o; o >>= 1) { s1 += __shfl_down(s1, o); s2 += __shfl_down(s2, o); }
    __shared__ float a1[4], a2[4], mv[2];
    if ((t & 63) == 0) { a1[t >> 6] = s1; a2[t >> 6] = s2; }
    __syncthreads();
    if (t == 0) {
        float S1 = a1[0] + a1[1] + a1[2] + a1[3];
        float S2 = a2[0] + a2[1] + a2[2] + a2[3];
        float mu = S1 / 512.f;
        mv[0] = mu;
        mv[1] = rsqrtf(S2 / 512.f - mu * mu + 1e-5f);
    }
    __syncthreads();
    int e = pair_e[p];
    const float* ge = g + e * HID_DIM;
    const float* be = bb + e * HID_DIM;
    float mu = mv[0], ir = mv[1];
    float n0 = (y0 - mu) * ir * ge[t] + be[t];
    float n1 = (y1 - mu) * ir * ge[t + 256] + be[t + 256];
    unsigned short* orow = hidb + (size_t)p * HID_DIM;
    orow[t]       = f2bf(0.5f * n0 * (1.f + erff(n0 * 0.70710678118654752f)));
    orow[t + 256] = f2bf(0.5f * n1 * (1.f + erff(n1 * 0.70710678118654752f)));
}

// ---------------- bf16 MFMA grouped GEMM, 128x128x32 tile, 4 waves,
// 2-phase double-buffered LDS with counted vmcnt (T3-min) + XCD group swizzle (T1)
// MODE 0: Cf=acc+bias   MODE 1: Cb=bf16(acc+bias)
// MODE 2: atomic out += pw*act(acc+bias), z = o-major (o=obase+z/8, e=z%8)
// MODE 4: split-K partial: Cf[kh*B_TOK*ldc + p*ldc+col] = acc (no bias), z = kh
template<int MODE, bool SPLIT>
__global__ __launch_bounds__(256)
void k_mm(const unsigned short* __restrict__ A, const unsigned short* __restrict__ Alo,
          int lda, int rowshift, int acol0,
          const unsigned short* __restrict__ Wp, const unsigned short* __restrict__ Wlo,
          size_t wstride,
          const float* __restrict__ bias, int bstride,
          float* __restrict__ Cf, unsigned short* __restrict__ Cb, int ldc,
          const int* __restrict__ lists, const int* __restrict__ counts, int Mfix,
          int N, int Kdim, int nz_e, int obase,
          float* __restrict__ outp, const float* __restrict__ pw) {
    // ---- XCD swizzle: group G = (m-tile, z); all n-tiles of G contiguous on one XCD.
    const int gx = gridDim.x, gy = gridDim.y;
    unsigned f = blockIdx.x + gx * (blockIdx.y + gy * blockIdx.z);
    unsigned xcd = f & 7u, s = f >> 3;
    unsigned G = xcd + 8u * (s / gx);
    const int bx = s % gx;
    const int byy = G % gy;
    const int bz  = G / gy;

    const int e  = bz % nz_e;
    const int zq = bz / nz_e;
    const int kh = (MODE == 4) ? bz : 0;
    const int o  = (MODE == 2) ? (obase + zq) : 0;
    const int cnt = counts ? counts[e] : Mfix;
    const int m0 = byy * 128;
    if (m0 >= cnt) return;
    const int n0 = bx * 128;

    const size_t woff = (MODE == 2) ? (size_t)bz * wstride
                                    : ((size_t)e * wstride + (size_t)kh * Kdim * N);
    const unsigned short* W  = Wp + woff;
    const unsigned short* Wl = SPLIT ? (Wlo + woff) : nullptr;
    const float* bptr = (MODE == 4) ? nullptr
                       : bias + (MODE == 2 ? (size_t)(o * E_NUM + e) * bstride
                                           : (size_t)e * bstride);
    const int acol = acol0 + (MODE == 2 ? o * D_DIM : kh * Kdim);
    const int* list = lists ? (lists + e * B_TOK) : nullptr;

    constexpr int BUFS = SPLIT ? 8192 : 4096;   // shorts per buffer
    __shared__ unsigned short Alds[2][BUFS];
    __shared__ unsigned short Blds[2][BUFS];

    const int tid  = threadIdx.x;
    const int lane = tid & 63;
    const int wid  = tid >> 6;
    const int c0 = wid * 64 + lane;
    const int c1 = c0 + 256;

    size_t aoff0, aoff1;
    {
        int r = m0 + (c0 & 127);
        int p = (r < cnt) ? (list ? list[r] : r) : 0;
        aoff0 = (size_t)(p >> rowshift) * lda + acol + (c0 >> 7) * 8;
        r = m0 + (c1 & 127);
        p = (r < cnt) ? (list ? list[r] : r) : 0;
        aoff1 = (size_t)(p >> rowshift) * lda + acol + (c1 >> 7) * 8;
    }
    const unsigned short* a0 = A + aoff0;
    const unsigned short* a1 = A + aoff1;
    const unsigned short* al0 = SPLIT ? (Alo + aoff0) : nullptr;
    const unsigned short* al1 = SPLIT ? (Alo + aoff1) : nullptr;
    const unsigned short* b0 = W + ((size_t)(c0 >> 7) * N + n0 + (c0 & 127)) * 8;
    const unsigned short* b1 = W + ((size_t)(c1 >> 7) * N + n0 + (c1 & 127)) * 8;
    const unsigned short* bl0 = SPLIT ? (Wl + ((size_t)(c0 >> 7) * N + n0 + (c0 & 127)) * 8) : nullptr;
    const unsigned short* bl1 = SPLIT ? (Wl + ((size_t)(c1 >> 7) * N + n0 + (c1 & 127)) * 8) : nullptr;

    const int d0 = (wid * 64) * 8;          // LDS dest base (shorts) for chunk c0
    const int d1 = (256 + wid * 64) * 8;    // for chunk c1
    const size_t bstep = (size_t)32 * N;

    auto stage = [&](int buf) {
        glds16(a0, &Alds[buf][d0]);
        glds16(a1, &Alds[buf][d1]);
        glds16(b0, &Blds[buf][d0]);
        glds16(b1, &Blds[buf][d1]);
        if constexpr (SPLIT) {
            glds16(al0, &Alds[buf][4096 + d0]);
            glds16(al1, &Alds[buf][4096 + d1]);
            glds16(bl0, &Blds[buf][4096 + d0]);
            glds16(bl1, &Blds[buf][4096 + d1]);
            al0 += 32; al1 += 32; bl0 += bstep; bl1 += bstep;
        }
        a0 += 32; a1 += 32; b0 += bstep; b1 += bstep;
    };

    const int wm = wid >> 1, wn = wid & 1;
    const int lr = lane & 15, lg = lane >> 4;

    f32x4 acc[4][4];
#pragma unroll
    for (int i = 0; i < 4; ++i)
#pragma unroll
        for (int j = 0; j < 4; ++j) acc[i][j] = (f32x4){0.f, 0.f, 0.f, 0.f};

    const int niter = Kdim / 32;
    int cur = 0;
    stage(0);
    for (int it = 0; it < niter; ++it) {
        if (it + 1 < niter) {
            stage(cur ^ 1);
            if constexpr (SPLIT) asm volatile("s_waitcnt vmcnt(8)" ::: "memory");
            else                 asm volatile("s_waitcnt vmcnt(4)" ::: "memory");
        } else {
            asm volatile("s_waitcnt vmcnt(0)" ::: "memory");
        }
        __builtin_amdgcn_s_barrier();          // cur tile resident for all waves
        __builtin_amdgcn_sched_barrier(0);

        bf16x8 af[4], bfr[4];
#pragma unroll
        for (int i = 0; i < 4; ++i)
            af[i] = *(const bf16x8*)&Alds[cur][((lg << 7) + wm * 64 + i * 16 + lr) * 8];
#pragma unroll
        for (int i = 0; i < 4; ++i)
            bfr[i] = *(const bf16x8*)&Blds[cur][((lg << 7) + wn * 64 + i * 16 + lr) * 8];
#pragma unroll
        for (int mi = 0; mi < 4; ++mi)
#pragma unroll
            for (int ni = 0; ni < 4; ++ni)
                acc[mi][ni] = __builtin_amdgcn_mfma_f32_16x16x32_bf16(af[mi], bfr[ni], acc[mi][ni], 0, 0, 0);
        if constexpr (SPLIT) {
            bf16x8 afl[4], bfl[4];
#pragma unroll
            for (int i = 0; i < 4; ++i)
                afl[i] = *(const bf16x8*)&Alds[cur][4096 + ((lg << 7) + wm * 64 + i * 16 + lr) * 8];
#pragma unroll
            for (int i = 0; i < 4; ++i)
                bfl[i] = *(const bf16x8*)&Blds[cur][4096 + ((lg << 7) + wn * 64 + i * 16 + lr) * 8];
#pragma unroll
            for (int mi = 0; mi < 4; ++mi)
#pragma unroll
                for (int ni = 0; ni < 4; ++ni) {
                    acc[mi][ni] = __builtin_amdgcn_mfma_f32_16x16x32_bf16(af[mi],  bfl[ni], acc[mi][ni], 0, 0, 0);
                    acc[mi][ni] = __builtin_amdgcn_mfma_f32_16x16x32_bf16(afl[mi], bfr[ni], acc[mi][ni], 0, 0, 0);
                }
        }
        __builtin_amdgcn_sched_barrier(0);
        __builtin_amdgcn_s_barrier();          // all waves done reading cur
        cur ^= 1;
    }

    float bv[4];
#pragma unroll
    for (int ni = 0; ni < 4; ++ni)
        bv[ni] = (MODE == 4) ? 0.f : bptr[n0 + wn * 64 + ni * 16 + lr];

#pragma unroll
    for (int mi = 0; mi < 4; ++mi) {
        int rbase = m0 + wm * 64 + mi * 16 + lg * 4;
#pragma unroll
        for (int rg = 0; rg < 4; ++rg) {
            int r = rbase + rg;
            if (r >= cnt) continue;
            int p = list ? list[r] : r;
#pragma unroll
            for (int ni = 0; ni < 4; ++ni) {
                int col = n0 + wn * 64 + ni * 16 + lr;
                float v = acc[mi][ni][rg] + bv[ni];
                if (MODE == 0) {
                    Cf[(size_t)p * ldc + col] = v;
                } else if (MODE == 1) {
                    Cb[(size_t)p * ldc + col] = f2bf(v);
                } else if (MODE == 4) {
                    Cf[(size_t)kh * B_TOK * RH_DIM + (size_t)p * ldc + col] = v;
                } else {
                    int token = p >> 1;
                    atomicAdd(outp + (size_t)o * B_TOK * D_DIM + (size_t)token * D_DIM + col,
                              pw[p] * apply_act(v, o));
                }
            }
        }
    }
}

extern "C" void kernel_launch(void* const* d_in, const int* in_sizes, int n_in,
                              void* d_out, int out_size, void* d_ws, size_t ws_size,
                              hipStream_t stream) {
    const float* h         = (const float*)d_in[0];
    const float* x         = (const float*)d_in[1];
    const int*   lidx      = (const int*)d_in[2];
    const float* layer_emb = (const float*)d_in[3];
    const float* phase_emb = (const float*)d_in[4];
    const float* Wr1       = (const float*)d_in[5];
    const float* br1       = (const float*)d_in[6];
    const float* lnr_g     = (const float*)d_in[7];
    const float* lnr_b     = (const float*)d_in[8];
    const float* Wr2       = (const float*)d_in[9];
    const float* br2       = (const float*)d_in[10];
    const float* W1        = (const float*)d_in[11];
    const float* b1        = (const float*)d_in[12];
    const float* ln1g      = (const float*)d_in[13];
    const float* ln1b      = (const float*)d_in[14];
    const float* W2        = (const float*)d_in[15];
    const float* b2        = (const float*)d_in[16];
    const float* Wa        = (const float*)d_in[17];
    const float* ba        = (const float*)d_in[18];
    const float* Wb_       = (const float*)d_in[19];
    const float* bbv       = (const float*)d_in[20];
    const float* Wg        = (const float*)d_in[21];
    const float* bg        = (const float*)d_in[22];
    const float* Wv        = (const float*)d_in[23];
    const float* bv        = (const float*)d_in[24];
    float* out = (float*)d_out;

    char* ws = (char*)d_ws;
    size_t off = 0;
    auto alloc = [&](size_t nb) { void* p = ws + off; off = (off + nb + 255) & ~(size_t)255; return p; };
    float*          rconstp = (float*)alloc(RH_DIM * 4);
    int*            pair_e  = (int*)alloc(NPAIR * 4);
    float*          pair_w  = (float*)alloc(NPAIR * 4);
    int*            counts  = (int*)alloc(64);
    int*            lists   = (int*)alloc((size_t)E_NUM * B_TOK * 4);
    float*          bcat    = (float*)alloc((size_t)4 * E_NUM * D_DIM * 4);       // 128 KB
    unsigned short* hx_hi   = (unsigned short*)alloc((size_t)B_TOK * 2048 * 2);   // 16.8 MB
    unsigned short* hid_bf  = (unsigned short*)alloc((size_t)NPAIR * 512 * 2);    // 8.4 MB
    unsigned short* wsc_hi  = (unsigned short*)alloc((size_t)8 * 512 * 4096 * 2); // 33.6 MB
    unsigned short* wsc_lo  = (unsigned short*)alloc((size_t)2048 * 256 * 2);     // 1 MB
    char*           featsR  = (char*)alloc((size_t)NPAIR * 4096 * 2);             // 67.1 MB
    // aliases inside featsR (disjoint lifetimes):
    float*          Pf      = (float*)featsR;                                 // [0,16.8MB) split-K partials, dead after k_route
    float*          hidf    = (float*)(featsR + ((size_t)17 << 20));          // [17,33.8MB) dead after k_lngelu
    unsigned short* hx_lo   = (unsigned short*)(featsR + ((size_t)34 << 20)); // [34,50.8MB) dead after routing mm
    unsigned short* feats   = (unsigned short*)featsR;                        // layer2 output

    (void)hipMemsetAsync(d_out, 0, (size_t)out_size * 4, stream);
    (void)hipMemsetAsync(counts, 0, 64, stream);
    (void)hipMemcpyAsync(bcat + 0 * E_NUM * D_DIM, ba,  (size_t)E_NUM * D_DIM * 4, hipMemcpyDeviceToDevice, stream);
    (void)hipMemcpyAsync(bcat + 1 * E_NUM * D_DIM, bbv, (size_t)E_NUM * D_DIM * 4, hipMemcpyDeviceToDevice, stream);
    (void)hipMemcpyAsync(bcat + 2 * E_NUM * D_DIM, bg,  (size_t)E_NUM * D_DIM * 4, hipMemcpyDeviceToDevice, stream);
    (void)hipMemcpyAsync(bcat + 3 * E_NUM * D_DIM, bv,  (size_t)E_NUM * D_DIM * 4, hipMemcpyDeviceToDevice, stream);

    // ---- routing path: split-K x4 partials (deterministic fixed-order combine)
    k_hxbf<<<4096, 256, 0, stream>>>(h, x, hx_hi, hx_lo);
    k_convW<true><<<dim3(1, 256, 1), 256, 0, stream>>>(Wr1, nullptr, wsc_hi, wsc_lo, 2048, RH_DIM, 1);
    k_rconst<<<1, 256, 0, stream>>>(layer_emb, phase_emb, lidx, Wr1, br1, rconstp);
    k_mm<4, true><<<dim3(2, 32, 4), 256, 0, stream>>>(
        hx_hi, hx_lo, 2048, 0, 0, wsc_hi, wsc_lo, 0, nullptr, 0,
        Pf, nullptr, RH_DIM, nullptr, nullptr, B_TOK, RH_DIM, 512, 1, 0,
        nullptr, nullptr);
    k_route<<<B_TOK, 256, 0, stream>>>(Pf, rconstp, lnr_g, lnr_b, Wr2, br2,
                                       pair_e, pair_w, lists, counts);

    // ---- layer1: hidf[p](512) = hx[token] @ W1[e] + b1[e]
    k_convW<false><<<dim3(2, 256, 8), 256, 0, stream>>>(W1, nullptr, wsc_hi, nullptr, 2048, HID_DIM, 8);
    k_mm<0, false><<<dim3(4, 32, 8), 256, 0, stream>>>(
        hx_hi, nullptr, 2048, 1, 0, wsc_hi, nullptr, (size_t)2048 * HID_DIM, b1, HID_DIM,
        hidf, nullptr, HID_DIM, lists, counts, 0, HID_DIM, 2048, 8, 0,
        nullptr, nullptr);
    k_lngelu<<<NPAIR, 256, 0, stream>>>(hidf, hid_bf, pair_e, ln1g, ln1b);

    // ---- layer2: feats[p](4096) = hid_bf[p] @ W2[e] + b2[e]  (bf16 out)
    k_convW<false><<<dim3(16, 64, 8), 256, 0, stream>>>(W2, nullptr, wsc_hi, nullptr, HID_DIM, 4096, 8);
    k_mm<1, false><<<dim3(32, 32, 8), 256, 0, stream>>>(
        hid_bf, nullptr, 512, 0, 0, wsc_hi, nullptr, (size_t)HID_DIM * 4096, b2, 4096,
        nullptr, feats, 4096, lists, counts, 0, 4096, HID_DIM, 8, 0,
        nullptr, nullptr);

    // ---- layer3, two fused halves: o in {0,1} then {2,3}
    k_convW<false><<<dim3(4, 128, 16), 256, 0, stream>>>(Wa, Wb_, wsc_hi, nullptr, D_DIM, D_DIM, 8);
    k_mm<2, false><<<dim3(8, 32, 16), 256, 0, stream>>>(
        feats, nullptr, 4096, 0, 0, wsc_hi, nullptr, (size_t)D_DIM * D_DIM, bcat, D_DIM,
        nullptr, nullptr, 0, lists, counts, 0, D_DIM, D_DIM, 8, 0,
        out, pair_w);
    k_convW<false><<<dim3(4, 128, 16), 256, 0, stream>>>(Wg, Wv, wsc_hi, nullptr, D_DIM, D_DIM, 8);
    k_mm<2, false><<<dim3(8, 32, 16), 256, 0, stream>>>(
        feats, nullptr, 4096, 0, 0, wsc_hi, nullptr, (size_t)D_DIM * D_DIM, bcat, D_DIM,
        nullptr, nullptr, 0, lists, counts, 0, D_DIM, D_DIM, 8, 2,
        out, pair_w);
}

// Round 6
// 591.556 us; speedup vs baseline: 4.1098x; 1.1913x over previous
//
#include <hip/hip_runtime.h>
#include <hip/hip_bf16.h>

#define B_TOK   4096
#define D_DIM   1024
#define E_NUM   8
#define HID_DIM 512
#define RH_DIM  256
#define EMB_DIM 32
#define NPAIR   (B_TOK * 2)   // 8192

typedef __attribute__((ext_vector_type(8))) short    bf16x8;
typedef __attribute__((ext_vector_type(8))) unsigned short u16x8;
typedef __attribute__((ext_vector_type(4))) float    f32x4;

__device__ __forceinline__ unsigned short f2bf(float f) {
    union { float f; unsigned u; } v; v.f = f;
    unsigned r = (v.u + 0x7fffu + ((v.u >> 16) & 1u)) >> 16;
    return (unsigned short)r;
}
__device__ __forceinline__ float bf2f(unsigned short b) {
    union { unsigned u; float f; } v; v.u = ((unsigned)b) << 16;
    return v.f;
}

__device__ __forceinline__ void glds16(const void* g, void* l) {
    __builtin_amdgcn_global_load_lds(
        (const __attribute__((address_space(1))) unsigned int*)g,
        (__attribute__((address_space(3))) unsigned int*)l, 16, 0, 0);
}

__device__ inline float apply_act(float v, int a) {
    if (a == 0 || a == 2) return 1.f / (1.f + expf(-v));        // sigmoid
    if (a == 1) return fmaxf(v, 0.f) + log1pf(expf(-fabsf(v))); // softplus
    return v;                                                    // identity
}

// ---------------- hx -> bf16 (hi + lo split), layout [token][2048]
__global__ void k_hxbf(const float* __restrict__ h, const float* __restrict__ x,
                       unsigned short* __restrict__ hi, unsigned short* __restrict__ lo) {
    int gid = blockIdx.x * 256 + threadIdx.x;
    int token = gid >> 8;
    int c0 = (gid & 255) * 8;
    const float* src = (c0 < 1024) ? (h + (size_t)token * 1024 + c0)
                                   : (x + (size_t)token * 1024 + c0 - 1024);
    u16x8 oh, ol;
#pragma unroll
    for (int j = 0; j < 8; ++j) {
        float f = src[j];
        unsigned short hb = f2bf(f);
        oh[j] = hb;
        ol[j] = f2bf(f - bf2f(hb));
    }
    size_t o = (size_t)gid * 8;
    *(u16x8*)(hi + o) = oh;
    *(u16x8*)(lo + o) = ol;
}

// ---------------- W [K][N] fp32 -> permuted bf16 [K/8][N][8]; z = matrix*eper + e
template<bool SPLIT>
__global__ void k_convW(const float* __restrict__ in0, const float* __restrict__ in1,
                        const float* __restrict__ in2, const float* __restrict__ in3,
                        unsigned short* __restrict__ oh, unsigned short* __restrict__ ol,
                        int K, int N, int eper) {
    int z = blockIdx.z;
    int e = z % eper, m = z / eper;
    const float* in = (m == 0 ? in0 : m == 1 ? in1 : m == 2 ? in2 : in3) + (size_t)e * K * N;
    int n  = blockIdx.x * 256 + threadIdx.x;
    int kg = blockIdx.y;
    const float* ip = in + (size_t)kg * 8 * N + n;
    u16x8 hv, lv;
#pragma unroll
    for (int j = 0; j < 8; ++j) {
        float f = ip[(size_t)j * N];
        unsigned short hb = f2bf(f);
        hv[j] = hb;
        if (SPLIT) lv[j] = f2bf(f - bf2f(hb));
    }
    size_t o = (size_t)z * K * N + ((size_t)kg * N + n) * 8;
    *(u16x8*)(oh + o) = hv;
    if (SPLIT) *(u16x8*)(ol + o) = lv;
}

// ---------------- routing const: br1 + le@Wr1[2048:2080] + pe@Wr1[2080:2112]
__global__ void k_rconst(const float* __restrict__ layer_emb,
                         const float* __restrict__ phase_emb,
                         const int* __restrict__ lidx,
                         const float* __restrict__ Wr1,
                         const float* __restrict__ br1,
                         float* __restrict__ rconst) {
    int j = threadIdx.x;
    int li = lidx[0];
    float acc = br1[j];
    for (int t = 0; t < EMB_DIM; ++t)
        acc += layer_emb[li * EMB_DIM + t] * Wr1[(2048 + t) * RH_DIM + j];
    for (int t = 0; t < EMB_DIM; ++t)
        acc += phase_emb[t] * Wr1[(2080 + t) * RH_DIM + j];
    rconst[j] = acc;
}

// ---------------- routing tail: sum 4 split-K partials (fixed order) + rconst,
// then LN + gelu + logits(parallel) + top2 + lists
__global__ void k_route(const float* __restrict__ Pf, const float* __restrict__ rconst,
                        const float* __restrict__ lnr_g, const float* __restrict__ lnr_b,
                        const float* __restrict__ Wr2, const float* __restrict__ br2,
                        float* __restrict__ pair_w,
                        int* __restrict__ lists, int* __restrict__ counts) {
    int b = blockIdx.x, t = threadIdx.x;
    __shared__ float sv[RH_DIM];
    __shared__ float a1[4], a2[4], mv[2];
    __shared__ float wsum[4][E_NUM];
    __shared__ float lg[E_NUM];

    size_t idx = (size_t)b * RH_DIM + t;
    const size_t kstride = (size_t)B_TOK * RH_DIM;
    float y = ((Pf[idx] + Pf[idx + kstride]) + (Pf[idx + 2 * kstride] + Pf[idx + 3 * kstride]))
              + rconst[t];
    float s1 = y, s2 = y * y;
    for (int o = 32; o; o >>= 1) { s1 += __shfl_down(s1, o); s2 += __shfl_down(s2, o); }
    if ((t & 63) == 0) { a1[t >> 6] = s1; a2[t >> 6] = s2; }
    __syncthreads();
    if (t == 0) {
        float S1 = a1[0] + a1[1] + a1[2] + a1[3];
        float S2 = a2[0] + a2[1] + a2[2] + a2[3];
        float mu = S1 / 256.f;
        mv[0] = mu;
        mv[1] = rsqrtf(S2 / 256.f - mu * mu + 1e-5f);
    }
    __syncthreads();
    float n = (y - mv[0]) * mv[1] * lnr_g[t] + lnr_b[t];
    sv[t] = 0.5f * n * (1.f + erff(n * 0.70710678118654752f));
    __syncthreads();

    {
        int e = t & 7, c = t >> 3;
        float part = 0.f;
#pragma unroll
        for (int jj = 0; jj < 8; ++jj)
            part += sv[c * 8 + jj] * Wr2[(c * 8 + jj) * E_NUM + e];
        part += __shfl_down(part, 8);
        part += __shfl_down(part, 16);
        part += __shfl_down(part, 32);
        if ((t & 63) < 8) wsum[t >> 6][e] = part;
    }
    __syncthreads();
    if (t < E_NUM)
        lg[t] = br2[t] + wsum[0][t] + wsum[1][t] + wsum[2][t] + wsum[3][t];
    __syncthreads();
    if (t == 0) {
        float v0 = -1e30f; int i0 = 0;
        for (int e = 0; e < E_NUM; ++e) if (lg[e] > v0) { v0 = lg[e]; i0 = e; }
        float v1 = -1e30f; int i1 = 0;
        for (int e = 0; e < E_NUM; ++e) if (e != i0 && lg[e] > v1) { v1 = lg[e]; i1 = e; }
        float e1 = expf(v1 - v0);
        pair_w[2 * b] = 1.f / (1.f + e1);
        pair_w[2 * b + 1] = e1 / (1.f + e1);
        int p0 = atomicAdd(&counts[i0], 1); lists[i0 * B_TOK + p0] = 2 * b;
        int p1 = atomicAdd(&counts[i1], 1); lists[i1 * B_TOK + p1] = 2 * b + 1;
    }
}

// ---------------- tiny: exclusive prefix over 8 counts
__global__ void k_offs(const int* __restrict__ counts, int* __restrict__ offs) {
    if (threadIdx.x == 0) {
        int s = 0;
        for (int e = 0; e < E_NUM; ++e) { offs[e] = s; s += counts[e]; }
        offs[E_NUM] = s;
    }
}

// ---------------- sorted-row metadata: q -> pair id, q -> expert
__global__ void k_meta(const int* __restrict__ offs, const int* __restrict__ lists,
                       int* __restrict__ rowmap, int* __restrict__ row_e) {
    int q = blockIdx.x * 256 + threadIdx.x;
    int e = 0;
    while (e < E_NUM - 1 && q >= offs[e + 1]) ++e;
    rowmap[q] = lists[e * B_TOK + (q - offs[e])];
    row_e[q] = e;
}

// ---------------- combine layer1 split-K partials + bias, LN + gelu -> bf16
__global__ void k_lngelu(const float* __restrict__ hidp, const float* __restrict__ b1,
                         unsigned short* __restrict__ hidb, const int* __restrict__ row_e,
                         const float* __restrict__ g, const float* __restrict__ bb) {
    int q = blockIdx.x, t = threadIdx.x;
    int e = row_e[q];
    const size_t st = (size_t)NPAIR * HID_DIM;
    size_t o0 = (size_t)q * HID_DIM + t;
    float y0 = hidp[o0] + hidp[o0 + st] + b1[e * HID_DIM + t];
    float y1 = hidp[o0 + 256] + hidp[o0 + 256 + st] + b1[e * HID_DIM + t + 256];
    float s1 = y0 + y1, s2 = y0 * y0 + y1 * y1;
    for (int o = 32; o; o >>= 1) { s1 += __shfl_down(s1, o); s2 += __shfl_down(s2, o); }
    __shared__ float a1[4], a2[4], mv[2];
    if ((t & 63) == 0) { a1[t >> 6] = s1; a2[t >> 6] = s2; }
    __syncthreads();
    if (t == 0) {
        float S1 = a1[0] + a1[1] + a1[2] + a1[3];
        float S2 = a2[0] + a2[1] + a2[2] + a2[3];
        float mu = S1 / 512.f;
        mv[0] = mu;
        mv[1] = rsqrtf(S2 / 512.f - mu * mu + 1e-5f);
    }
    __syncthreads();
    const float* ge = g + e * HID_DIM;
    const float* be = bb + e * HID_DIM;
    float mu = mv[0], ir = mv[1];
    float n0 = (y0 - mu) * ir * ge[t] + be[t];
    float n1 = (y1 - mu) * ir * ge[t + 256] + be[t + 256];
    unsigned short* orow = hidb + (size_t)q * HID_DIM;
    orow[t]       = f2bf(0.5f * n0 * (1.f + erff(n0 * 0.70710678118654752f)));
    orow[t + 256] = f2bf(0.5f * n1 * (1.f + erff(n1 * 0.70710678118654752f)));
}

// ---------------- bf16 MFMA grouped GEMM, 128x128x32 tile, 4 waves
// NBUF-deep LDS pipeline with counted vmcnt; XCD group swizzle (T1);
// coalesced A-staging: A-tile LDS layout [row][4 slots][8] (64B rows ->
// stride-64B ds_read_b128 is inherently conflict-free; NO swizzle).
// MODE 1: Cb[q] = bf16(acc+bias)        (sorted rows)
// MODE 2: atomic out[o][token] += pw*act(acc+bias), z = o*8+e, scatter rowmap
// MODE 4: Cf[(kh*B_TOK + row)] = acc    (dense rows, z = kh)
// MODE 5: Cf[(kh*NPAIR + q)]  = acc     (sorted rows, z = kh*8+e, A gathered)
template<int MODE, bool SPLIT, bool AGATHER, int NBUF>
__global__ __launch_bounds__(256)
void k_mm(const unsigned short* __restrict__ A, const unsigned short* __restrict__ Alo,
          int lda, int rowshift, int acol0,
          const unsigned short* __restrict__ Wp, const unsigned short* __restrict__ Wlo,
          size_t wstride,
          const float* __restrict__ bias, int bstride,
          float* __restrict__ Cf, unsigned short* __restrict__ Cb, int ldc,
          const int* __restrict__ offs, const int* __restrict__ counts,
          const int* __restrict__ rowmap, int Mfix,
          int N, int Kdim, int nz_e,
          float* __restrict__ outp, const float* __restrict__ pw) {
    // ---- XCD swizzle: group G = (m-tile, z); all n-tiles of G on one XCD
    const int gx = gridDim.x, gy = gridDim.y;
    unsigned fb = blockIdx.x + gx * (blockIdx.y + gy * blockIdx.z);
    unsigned xcd = fb & 7u, sb = fb >> 3;
    unsigned G = xcd + 8u * (sb / gx);
    const int bx  = sb % gx;
    const int byy = G % gy;
    const int bz  = G / gy;

    const int e  = bz % nz_e;
    const int zq = bz / nz_e;          // kh (MODE 4/5) or o (MODE 2)
    const int cnt = counts ? counts[e] : Mfix;
    const int m0 = byy * 128;
    if (m0 >= cnt) return;
    const int n0 = bx * 128;
    const int base = offs ? offs[e] : 0;

    const size_t woff = (MODE == 2) ? (size_t)bz * wstride
                                    : (size_t)e * wstride + (size_t)zq * Kdim * N;
    const unsigned short* W  = Wp + woff;
    const unsigned short* Wl = SPLIT ? (Wlo + woff) : nullptr;
    const float* bptr = (MODE == 1) ? bias + (size_t)e * bstride
                      : (MODE == 2) ? bias + (size_t)bz * bstride : nullptr;
    const int acol = acol0 + zq * Kdim;

    constexpr int ABUF = SPLIT ? 8192 : 4096;
    __shared__ unsigned short Alds[NBUF][ABUF];   // A: [row][4 slots][8]
    __shared__ unsigned short Blds[NBUF][ABUF];   // B: [kg][128][8]

    const int tid  = threadIdx.x;
    const int lane = tid & 63;
    const int wid  = tid >> 6;
    const int c0 = tid, c1 = tid + 256;
    const int r0 = c0 >> 2, r1 = c1 >> 2;

    auto aoff_of = [&](int r, int cq) -> size_t {
        int rr = m0 + r; if (rr >= cnt) rr = cnt - 1;
        int qg = base + rr;
        int row = AGATHER ? (rowmap[qg] >> rowshift) : qg;
        return (size_t)row * lda + acol + (cq << 3);
    };
    size_t aoff0 = aoff_of(r0, c0 & 3);
    size_t aoff1 = aoff_of(r1, c1 & 3);
    const unsigned short* a0 = A + aoff0;
    const unsigned short* a1 = A + aoff1;
    const unsigned short* al0 = SPLIT ? Alo + aoff0 : nullptr;
    const unsigned short* al1 = SPLIT ? Alo + aoff1 : nullptr;
    size_t boff0 = ((size_t)(c0 >> 7) * N + n0 + (c0 & 127)) * 8;
    size_t boff1 = ((size_t)(c1 >> 7) * N + n0 + (c1 & 127)) * 8;
    const unsigned short* b0 = W + boff0;
    const unsigned short* b1 = W + boff1;
    const unsigned short* bl0 = SPLIT ? Wl + boff0 : nullptr;
    const unsigned short* bl1 = SPLIT ? Wl + boff1 : nullptr;

    const int d0 = c0 * 8, d1 = c1 * 8;
    const size_t bstep = (size_t)32 * N;

    auto stage = [&](int buf) {
        glds16(a0, &Alds[buf][d0]);
        glds16(a1, &Alds[buf][d1]);
        glds16(b0, &Blds[buf][d0]);
        glds16(b1, &Blds[buf][d1]);
        if constexpr (SPLIT) {
            glds16(al0, &Alds[buf][4096 + d0]);
            glds16(al1, &Alds[buf][4096 + d1]);
            glds16(bl0, &Blds[buf][4096 + d0]);
            glds16(bl1, &Blds[buf][4096 + d1]);
            al0 += 32; al1 += 32; bl0 += bstep; bl1 += bstep;
        }
        a0 += 32; a1 += 32; b0 += bstep; b1 += bstep;
    };

    const int wm = wid >> 1, wn = wid & 1;
    const int lr = lane & 15, lg = lane >> 4;
    const int aslot = lg << 3;     // shorts: k-chunk slot within the 32-short row

    f32x4 acc[4][4];
#pragma unroll
    for (int i = 0; i < 4; ++i)
#pragma unroll
        for (int j = 0; j < 4; ++j) acc[i][j] = (f32x4){0.f, 0.f, 0.f, 0.f};

    const int niter = Kdim / 32;
    for (int s = 0; s < NBUF - 1; ++s) stage(s);

    int cur = 0, nxt = NBUF - 1;
    for (int it = 0; it < niter; ++it) {
        if (it + NBUF - 1 < niter) {
            stage(nxt);
            nxt = (nxt + 1 == NBUF) ? 0 : nxt + 1;
        }
        int rem = niter - 1 - it; if (rem > NBUF - 1) rem = NBUF - 1;
        rem *= (SPLIT ? 8 : 4);
        if (rem >= 8)      asm volatile("s_waitcnt vmcnt(8)" ::: "memory");
        else if (rem >= 4) asm volatile("s_waitcnt vmcnt(4)" ::: "memory");
        else               asm volatile("s_waitcnt vmcnt(0)" ::: "memory");
        __builtin_amdgcn_s_barrier();
        __builtin_amdgcn_sched_barrier(0);

        bf16x8 af[4], bfr[4];
#pragma unroll
        for (int i = 0; i < 4; ++i)
            af[i] = *(const bf16x8*)&Alds[cur][(wm * 64 + i * 16 + lr) * 32 + aslot];
#pragma unroll
        for (int i = 0; i < 4; ++i)
            bfr[i] = *(const bf16x8*)&Blds[cur][((lg << 7) + wn * 64 + i * 16 + lr) * 8];
#pragma unroll
        for (int mi = 0; mi < 4; ++mi)
#pragma unroll
            for (int ni = 0; ni < 4; ++ni)
                acc[mi][ni] = __builtin_amdgcn_mfma_f32_16x16x32_bf16(af[mi], bfr[ni], acc[mi][ni], 0, 0, 0);
        if constexpr (SPLIT) {
            bf16x8 afl[4], bfl[4];
#pragma unroll
            for (int i = 0; i < 4; ++i)
                afl[i] = *(const bf16x8*)&Alds[cur][4096 + (wm * 64 + i * 16 + lr) * 32 + aslot];
#pragma unroll
            for (int i = 0; i < 4; ++i)
                bfl[i] = *(const bf16x8*)&Blds[cur][4096 + ((lg << 7) + wn * 64 + i * 16 + lr) * 8];
#pragma unroll
            for (int mi = 0; mi < 4; ++mi)
#pragma unroll
                for (int ni = 0; ni < 4; ++ni) {
                    acc[mi][ni] = __builtin_amdgcn_mfma_f32_16x16x32_bf16(af[mi],  bfl[ni], acc[mi][ni], 0, 0, 0);
                    acc[mi][ni] = __builtin_amdgcn_mfma_f32_16x16x32_bf16(afl[mi], bfr[ni], acc[mi][ni], 0, 0, 0);
                }
        }
        __builtin_amdgcn_sched_barrier(0);
        __builtin_amdgcn_s_barrier();
        cur = (cur + 1 == NBUF) ? 0 : cur + 1;
    }

    float bv[4];
#pragma unroll
    for (int ni = 0; ni < 4; ++ni)
        bv[ni] = (MODE == 1 || MODE == 2) ? bptr[n0 + wn * 64 + ni * 16 + lr] : 0.f;

#pragma unroll
    for (int mi = 0; mi < 4; ++mi) {
        int rbase = m0 + wm * 64 + mi * 16 + lg * 4;
#pragma unroll
        for (int rg = 0; rg < 4; ++rg) {
            int r = rbase + rg;
            if (r >= cnt) continue;
            int q = base + r;
#pragma unroll
            for (int ni = 0; ni < 4; ++ni) {
                int col = n0 + wn * 64 + ni * 16 + lr;
                float v = acc[mi][ni][rg] + bv[ni];
                if (MODE == 1) {
                    Cb[(size_t)q * ldc + col] = f2bf(v);
                } else if (MODE == 4) {
                    Cf[((size_t)zq * B_TOK + q) * ldc + col] = v;
                } else if (MODE == 5) {
                    Cf[((size_t)zq * NPAIR + q) * ldc + col] = v;
                } else {  // MODE 2
                    int p = rowmap[q];
                    atomicAdd(outp + ((size_t)zq * B_TOK + (p >> 1)) * D_DIM + col,
                              pw[p] * apply_act(v, zq));
                }
            }
        }
    }
}

extern "C" void kernel_launch(void* const* d_in, const int* in_sizes, int n_in,
                              void* d_out, int out_size, void* d_ws, size_t ws_size,
                              hipStream_t stream) {
    const float* h         = (const float*)d_in[0];
    const float* x         = (const float*)d_in[1];
    const int*   lidx      = (const int*)d_in[2];
    const float* layer_emb = (const float*)d_in[3];
    const float* phase_emb = (const float*)d_in[4];
    const float* Wr1       = (const float*)d_in[5];
    const float* br1       = (const float*)d_in[6];
    const float* lnr_g     = (const float*)d_in[7];
    const float* lnr_b     = (const float*)d_in[8];
    const float* Wr2       = (const float*)d_in[9];
    const float* br2       = (const float*)d_in[10];
    const float* W1        = (const float*)d_in[11];
    const float* b1        = (const float*)d_in[12];
    const float* ln1g      = (const float*)d_in[13];
    const float* ln1b      = (const float*)d_in[14];
    const float* W2        = (const float*)d_in[15];
    const float* b2        = (const float*)d_in[16];
    const float* Wa        = (const float*)d_in[17];
    const float* ba        = (const float*)d_in[18];
    const float* Wb_       = (const float*)d_in[19];
    const float* bbv       = (const float*)d_in[20];
    const float* Wg        = (const float*)d_in[21];
    const float* bg        = (const float*)d_in[22];
    const float* Wv        = (const float*)d_in[23];
    const float* bv        = (const float*)d_in[24];
    float* out = (float*)d_out;

    char* ws = (char*)d_ws;
    size_t off = 0;
    auto alloc = [&](size_t nb) { void* p = ws + off; off = (off + nb + 255) & ~(size_t)255; return p; };
    float*          rconstp = (float*)alloc(RH_DIM * 4);
    float*          pair_w  = (float*)alloc(NPAIR * 4);
    int*            counts  = (int*)alloc(64);
    int*            offs    = (int*)alloc(64);
    int*            lists   = (int*)alloc((size_t)E_NUM * B_TOK * 4);
    int*            rowmap  = (int*)alloc(NPAIR * 4);
    int*            row_e   = (int*)alloc(NPAIR * 4);
    float*          bcat    = (float*)alloc((size_t)4 * E_NUM * D_DIM * 4);        // 128 KB
    unsigned short* hx_hi   = (unsigned short*)alloc((size_t)B_TOK * 2048 * 2);    // 16 MiB
    unsigned short* hid_bf  = (unsigned short*)alloc((size_t)NPAIR * HID_DIM * 2); // 8 MiB
    char*           featsR  = (char*)alloc((size_t)NPAIR * 4096 * 2);              // 64 MiB
    unsigned short* wsc_hi  = (unsigned short*)alloc((size_t)4 * E_NUM * D_DIM * D_DIM * 2); // 64 MiB
    unsigned short* wsc_lo  = (unsigned short*)alloc((size_t)2048 * RH_DIM * 2);   // 1 MiB
    // aliases inside featsR (disjoint lifetimes):
    float*          Pf      = (float*)featsR;                                  // [0,16M)  dead after k_route
    float*          hidp    = (float*)(featsR + ((size_t)16 << 20));           // [16,48M) dead after k_lngelu
    unsigned short* hx_lo   = (unsigned short*)(featsR + ((size_t)48 << 20));  // [48,64M) dead after routing mm
    unsigned short* feats   = (unsigned short*)featsR;                         // layer2 output (full 64M)

    (void)hipMemsetAsync(d_out, 0, (size_t)out_size * 4, stream);
    (void)hipMemsetAsync(counts, 0, 64, stream);
    (void)hipMemcpyAsync(bcat + 0 * E_NUM * D_DIM, ba,  (size_t)E_NUM * D_DIM * 4, hipMemcpyDeviceToDevice, stream);
    (void)hipMemcpyAsync(bcat + 1 * E_NUM * D_DIM, bbv, (size_t)E_NUM * D_DIM * 4, hipMemcpyDeviceToDevice, stream);
    (void)hipMemcpyAsync(bcat + 2 * E_NUM * D_DIM, bg,  (size_t)E_NUM * D_DIM * 4, hipMemcpyDeviceToDevice, stream);
    (void)hipMemcpyAsync(bcat + 3 * E_NUM * D_DIM, bv,  (size_t)E_NUM * D_DIM * 4, hipMemcpyDeviceToDevice, stream);

    // ---- routing path: split-K x4 partials (deterministic fixed-order combine)
    k_hxbf<<<4096, 256, 0, stream>>>(h, x, hx_hi, hx_lo);
    k_convW<true><<<dim3(1, 256, 1), 256, 0, stream>>>(Wr1, nullptr, nullptr, nullptr,
                                                       wsc_hi, wsc_lo, 2048, RH_DIM, 1);
    k_rconst<<<1, 256, 0, stream>>>(layer_emb, phase_emb, lidx, Wr1, br1, rconstp);
    k_mm<4, true, false, 2><<<dim3(2, 32, 4), 256, 0, stream>>>(
        hx_hi, hx_lo, 2048, 0, 0, wsc_hi, wsc_lo, 0, nullptr, 0,
        Pf, nullptr, RH_DIM, nullptr, nullptr, nullptr, B_TOK,
        RH_DIM, 512, 1, nullptr, nullptr);
    k_route<<<B_TOK, 256, 0, stream>>>(Pf, rconstp, lnr_g, lnr_b, Wr2, br2,
                                       pair_w, lists, counts);
    k_offs<<<1, 64, 0, stream>>>(counts, offs);
    k_meta<<<NPAIR / 256, 256, 0, stream>>>(offs, lists, rowmap, row_e);

    // ---- layer1 (split-K x2, sorted C): hidp[kh][q](512) = hx[token] @ W1[e]
    k_convW<false><<<dim3(2, 256, 8), 256, 0, stream>>>(W1, nullptr, nullptr, nullptr,
                                                        wsc_hi, nullptr, 2048, HID_DIM, 8);
    k_mm<5, false, true, 3><<<dim3(4, 32, 16), 256, 0, stream>>>(
        hx_hi, nullptr, 2048, 1, 0, wsc_hi, nullptr, (size_t)2048 * HID_DIM, nullptr, 0,
        hidp, nullptr, HID_DIM, offs, counts, rowmap, 0,
        HID_DIM, 1024, 8, nullptr, nullptr);
    k_lngelu<<<NPAIR, 256, 0, stream>>>(hidp, b1, hid_bf, row_e, ln1g, ln1b);

    // ---- layer2: feats[q](4096) = hid_bf[q] @ W2[e] + b2[e]  (bf16 out, sorted)
    k_convW<false><<<dim3(16, 64, 8), 256, 0, stream>>>(W2, nullptr, nullptr, nullptr,
                                                        wsc_hi, nullptr, HID_DIM, 4096, 8);
    k_mm<1, false, false, 3><<<dim3(32, 32, 8), 256, 0, stream>>>(
        hid_bf, nullptr, HID_DIM, 0, 0, wsc_hi, nullptr, (size_t)HID_DIM * 4096, b2, 4096,
        nullptr, feats, 4096, offs, counts, nullptr, 0,
        4096, HID_DIM, 8, nullptr, nullptr);

    // ---- layer3, single launch (o,e fused; z = o*8+e):
    k_convW<false><<<dim3(4, 128, 32), 256, 0, stream>>>(Wa, Wb_, Wg, Wv,
                                                         wsc_hi, nullptr, D_DIM, D_DIM, 8);
    k_mm<2, false, false, 3><<<dim3(8, 32, 32), 256, 0, stream>>>(
        feats, nullptr, 4096, 0, 0, wsc_hi, nullptr, (size_t)D_DIM * D_DIM, bcat, D_DIM,
        nullptr, nullptr, 0, offs, counts, rowmap, 0,
        D_DIM, D_DIM, 8, out, pair_w);
}

// Round 7
// 569.975 us; speedup vs baseline: 4.2654x; 1.0379x over previous
//
#include <hip/hip_runtime.h>
#include <hip/hip_bf16.h>

#define B_TOK   4096
#define D_DIM   1024
#define E_NUM   8
#define HID_DIM 512
#define RH_DIM  256
#define EMB_DIM 32
#define NPAIR   (B_TOK * 2)   // 8192

typedef __attribute__((ext_vector_type(8))) short    bf16x8;
typedef __attribute__((ext_vector_type(8))) unsigned short u16x8;
typedef __attribute__((ext_vector_type(4))) unsigned short u16x4;
typedef __attribute__((ext_vector_type(4))) float    f32x4;

__device__ __forceinline__ unsigned short f2bf(float f) {
    union { float f; unsigned u; } v; v.f = f;
    unsigned r = (v.u + 0x7fffu + ((v.u >> 16) & 1u)) >> 16;
    return (unsigned short)r;
}
__device__ __forceinline__ float bf2f(unsigned short b) {
    union { unsigned u; float f; } v; v.u = ((unsigned)b) << 16;
    return v.f;
}

__device__ __forceinline__ void glds16(const void* g, void* l) {
    __builtin_amdgcn_global_load_lds(
        (const __attribute__((address_space(1))) unsigned int*)g,
        (__attribute__((address_space(3))) unsigned int*)l, 16, 0, 0);
}

__device__ inline float apply_act(float v, int a) {
    if (a == 0 || a == 2) return 1.f / (1.f + expf(-v));        // sigmoid
    if (a == 1) return fmaxf(v, 0.f) + log1pf(expf(-fabsf(v))); // softplus
    return v;                                                    // identity
}

// ---------------- hx -> bf16 (hi + lo split), layout [token][2048]
__global__ void k_hxbf(const float* __restrict__ h, const float* __restrict__ x,
                       unsigned short* __restrict__ hi, unsigned short* __restrict__ lo) {
    int gid = blockIdx.x * 256 + threadIdx.x;
    int token = gid >> 8;
    int c0 = (gid & 255) * 8;
    const float* src = (c0 < 1024) ? (h + (size_t)token * 1024 + c0)
                                   : (x + (size_t)token * 1024 + c0 - 1024);
    u16x8 oh, ol;
#pragma unroll
    for (int j = 0; j < 8; ++j) {
        float f = src[j];
        unsigned short hb = f2bf(f);
        oh[j] = hb;
        ol[j] = f2bf(f - bf2f(hb));
    }
    size_t o = (size_t)gid * 8;
    *(u16x8*)(hi + o) = oh;
    *(u16x8*)(lo + o) = ol;
}

// ---------------- W [K][N] fp32 -> permuted bf16 [K/8][N][8]; z = matrix*eper + e
template<bool SPLIT>
__global__ void k_convW(const float* __restrict__ in0, const float* __restrict__ in1,
                        const float* __restrict__ in2, const float* __restrict__ in3,
                        unsigned short* __restrict__ oh, unsigned short* __restrict__ ol,
                        int K, int N, int eper) {
    int z = blockIdx.z;
    int e = z % eper, m = z / eper;
    const float* in = (m == 0 ? in0 : m == 1 ? in1 : m == 2 ? in2 : in3) + (size_t)e * K * N;
    int n  = blockIdx.x * 256 + threadIdx.x;
    int kg = blockIdx.y;
    const float* ip = in + (size_t)kg * 8 * N + n;
    u16x8 hv, lv;
#pragma unroll
    for (int j = 0; j < 8; ++j) {
        float f = ip[(size_t)j * N];
        unsigned short hb = f2bf(f);
        hv[j] = hb;
        if (SPLIT) lv[j] = f2bf(f - bf2f(hb));
    }
    size_t o = (size_t)z * K * N + ((size_t)kg * N + n) * 8;
    *(u16x8*)(oh + o) = hv;
    if (SPLIT) *(u16x8*)(ol + o) = lv;
}

// ---------------- routing const: br1 + le@Wr1[2048:2080] + pe@Wr1[2080:2112]
__global__ void k_rconst(const float* __restrict__ layer_emb,
                         const float* __restrict__ phase_emb,
                         const int* __restrict__ lidx,
                         const float* __restrict__ Wr1,
                         const float* __restrict__ br1,
                         float* __restrict__ rconst) {
    int j = threadIdx.x;
    int li = lidx[0];
    float acc = br1[j];
    for (int t = 0; t < EMB_DIM; ++t)
        acc += layer_emb[li * EMB_DIM + t] * Wr1[(2048 + t) * RH_DIM + j];
    for (int t = 0; t < EMB_DIM; ++t)
        acc += phase_emb[t] * Wr1[(2080 + t) * RH_DIM + j];
    rconst[j] = acc;
}

// ---------------- routing tail: sum 4 split-K partials (fixed order) + rconst,
// then LN + gelu + logits(parallel) + top2 + lists
__global__ void k_route(const float* __restrict__ Pf, const float* __restrict__ rconst,
                        const float* __restrict__ lnr_g, const float* __restrict__ lnr_b,
                        const float* __restrict__ Wr2, const float* __restrict__ br2,
                        float* __restrict__ pair_w,
                        int* __restrict__ lists, int* __restrict__ counts) {
    int b = blockIdx.x, t = threadIdx.x;
    __shared__ float sv[RH_DIM];
    __shared__ float a1[4], a2[4], mv[2];
    __shared__ float wsum[4][E_NUM];
    __shared__ float lg[E_NUM];

    size_t idx = (size_t)b * RH_DIM + t;
    const size_t kstride = (size_t)B_TOK * RH_DIM;
    float y = ((Pf[idx] + Pf[idx + kstride]) + (Pf[idx + 2 * kstride] + Pf[idx + 3 * kstride]))
              + rconst[t];
    float s1 = y, s2 = y * y;
    for (int o = 32; o; o >>= 1) { s1 += __shfl_down(s1, o); s2 += __shfl_down(s2, o); }
    if ((t & 63) == 0) { a1[t >> 6] = s1; a2[t >> 6] = s2; }
    __syncthreads();
    if (t == 0) {
        float S1 = a1[0] + a1[1] + a1[2] + a1[3];
        float S2 = a2[0] + a2[1] + a2[2] + a2[3];
        float mu = S1 / 256.f;
        mv[0] = mu;
        mv[1] = rsqrtf(S2 / 256.f - mu * mu + 1e-5f);
    }
    __syncthreads();
    float n = (y - mv[0]) * mv[1] * lnr_g[t] + lnr_b[t];
    sv[t] = 0.5f * n * (1.f + erff(n * 0.70710678118654752f));
    __syncthreads();

    {
        int e = t & 7, c = t >> 3;
        float part = 0.f;
#pragma unroll
        for (int jj = 0; jj < 8; ++jj)
            part += sv[c * 8 + jj] * Wr2[(c * 8 + jj) * E_NUM + e];
        part += __shfl_down(part, 8);
        part += __shfl_down(part, 16);
        part += __shfl_down(part, 32);
        if ((t & 63) < 8) wsum[t >> 6][e] = part;
    }
    __syncthreads();
    if (t < E_NUM)
        lg[t] = br2[t] + wsum[0][t] + wsum[1][t] + wsum[2][t] + wsum[3][t];
    __syncthreads();
    if (t == 0) {
        float v0 = -1e30f; int i0 = 0;
        for (int e = 0; e < E_NUM; ++e) if (lg[e] > v0) { v0 = lg[e]; i0 = e; }
        float v1 = -1e30f; int i1 = 0;
        for (int e = 0; e < E_NUM; ++e) if (e != i0 && lg[e] > v1) { v1 = lg[e]; i1 = e; }
        float e1 = expf(v1 - v0);
        pair_w[2 * b] = 1.f / (1.f + e1);
        pair_w[2 * b + 1] = e1 / (1.f + e1);
        int p0 = atomicAdd(&counts[i0], 1); lists[i0 * B_TOK + p0] = 2 * b;
        int p1 = atomicAdd(&counts[i1], 1); lists[i1 * B_TOK + p1] = 2 * b + 1;
    }
}

// ---------------- tiny: exclusive prefix over 8 counts
__global__ void k_offs(const int* __restrict__ counts, int* __restrict__ offs) {
    if (threadIdx.x == 0) {
        int s = 0;
        for (int e = 0; e < E_NUM; ++e) { offs[e] = s; s += counts[e]; }
        offs[E_NUM] = s;
    }
}

// ---------------- sorted-row metadata: q -> pair id, q -> expert, pair -> q
__global__ void k_meta(const int* __restrict__ offs, const int* __restrict__ lists,
                       int* __restrict__ rowmap, int* __restrict__ row_e,
                       int* __restrict__ qof) {
    int q = blockIdx.x * 256 + threadIdx.x;
    int e = 0;
    while (e < E_NUM - 1 && q >= offs[e + 1]) ++e;
    int p = lists[e * B_TOK + (q - offs[e])];
    rowmap[q] = p;
    row_e[q] = e;
    qof[p] = q;
}

// ---------------- combine layer1 split-K partials + bias, LN + gelu -> bf16
__global__ void k_lngelu(const float* __restrict__ hidp, const float* __restrict__ b1,
                         unsigned short* __restrict__ hidb, const int* __restrict__ row_e,
                         const float* __restrict__ g, const float* __restrict__ bb) {
    int q = blockIdx.x, t = threadIdx.x;
    int e = row_e[q];
    const size_t st = (size_t)NPAIR * HID_DIM;
    size_t o0 = (size_t)q * HID_DIM + t;
    float y0 = hidp[o0] + hidp[o0 + st] + b1[e * HID_DIM + t];
    float y1 = hidp[o0 + 256] + hidp[o0 + 256 + st] + b1[e * HID_DIM + t + 256];
    float s1 = y0 + y1, s2 = y0 * y0 + y1 * y1;
    for (int o = 32; o; o >>= 1) { s1 += __shfl_down(s1, o); s2 += __shfl_down(s2, o); }
    __shared__ float a1[4], a2[4], mv[2];
    if ((t & 63) == 0) { a1[t >> 6] = s1; a2[t >> 6] = s2; }
    __syncthreads();
    if (t == 0) {
        float S1 = a1[0] + a1[1] + a1[2] + a1[3];
        float S2 = a2[0] + a2[1] + a2[2] + a2[3];
        float mu = S1 / 512.f;
        mv[0] = mu;
        mv[1] = rsqrtf(S2 / 512.f - mu * mu + 1e-5f);
    }
    __syncthreads();
    const float* ge = g + e * HID_DIM;
    const float* be = bb + e * HID_DIM;
    float mu = mv[0], ir = mv[1];
    float n0 = (y0 - mu) * ir * ge[t] + be[t];
    float n1 = (y1 - mu) * ir * ge[t + 256] + be[t + 256];
    unsigned short* orow = hidb + (size_t)q * HID_DIM;
    orow[t]       = f2bf(0.5f * n0 * (1.f + erff(n0 * 0.70710678118654752f)));
    orow[t + 256] = f2bf(0.5f * n1 * (1.f + erff(n1 * 0.70710678118654752f)));
}

// ---------------- final combine: out[o][token] = sel[o][q0] + sel[o][q1]
__global__ void k_comb(const unsigned short* __restrict__ sel,
                       const int* __restrict__ qof, float* __restrict__ out) {
    int b = blockIdx.x, o = blockIdx.y;
    int c = threadIdx.x * 4;
    int q0 = qof[2 * b], q1 = qof[2 * b + 1];
    size_t s0 = ((size_t)o * NPAIR + q0) * D_DIM + c;
    size_t s1 = ((size_t)o * NPAIR + q1) * D_DIM + c;
    u16x4 a = *(const u16x4*)(sel + s0);
    u16x4 bq = *(const u16x4*)(sel + s1);
    f32x4 r;
#pragma unroll
    for (int j = 0; j < 4; ++j) r[j] = bf2f(a[j]) + bf2f(bq[j]);
    *(f32x4*)(out + ((size_t)o * B_TOK + b) * D_DIM + c) = r;
}

// ---------------- bf16 MFMA grouped GEMM, 128x128x32 tile, 4 waves
// NBUF-deep LDS pipeline, counted vmcnt; XCD group swizzle (T1);
// coalesced A-staging, LDS [row][4 slots][8] with 2-bit slot XOR swizzle
// slot' = cq ^ ((row>>1)&3) applied BOTH at global source and LDS read
// (rule 21) -> per-16-lane-phase banks spread over all 8 windows (2-way, free).
// MODE 1: Cb[q] = bf16(acc+bias)        (sorted rows)
// MODE 2: atomic out[o][token] += pw*act(acc+bias), z = o*8+e (fallback)
// MODE 4: Cf[(kh*B_TOK + row)] = acc    (dense rows, z = kh)
// MODE 5: Cf[(kh*NPAIR + q)]  = acc     (sorted rows, z = kh*8+e, A gathered)
// MODE 6: Cb[(o*NPAIR + q)]   = bf16(pw*act(acc+bias)), z = o*8+e (sorted)
template<int MODE, bool SPLIT, bool AGATHER, int NBUF>
__global__ __launch_bounds__(256)
void k_mm(const unsigned short* __restrict__ A, const unsigned short* __restrict__ Alo,
          int lda, int rowshift, int acol0,
          const unsigned short* __restrict__ Wp, const unsigned short* __restrict__ Wlo,
          size_t wstride,
          const float* __restrict__ bias, int bstride,
          float* __restrict__ Cf, unsigned short* __restrict__ Cb, int ldc,
          const int* __restrict__ offs, const int* __restrict__ counts,
          const int* __restrict__ rowmap, int Mfix,
          int N, int Kdim, int nz_e,
          float* __restrict__ outp, const float* __restrict__ pw) {
    // ---- XCD swizzle: group G = (m-tile, z); all n-tiles of G on one XCD
    const int gx = gridDim.x, gy = gridDim.y;
    unsigned fb = blockIdx.x + gx * (blockIdx.y + gy * blockIdx.z);
    unsigned xcd = fb & 7u, sb = fb >> 3;
    unsigned G = xcd + 8u * (sb / gx);
    const int bx  = sb % gx;
    const int byy = G % gy;
    const int bz  = G / gy;

    const int e  = bz % nz_e;
    const int zq = bz / nz_e;          // kh (MODE 4/5) or o (MODE 2/6)
    const int cnt = counts ? counts[e] : Mfix;
    const int m0 = byy * 128;
    if (m0 >= cnt) return;
    const int n0 = bx * 128;
    const int base = offs ? offs[e] : 0;

    const size_t woff = (MODE == 2 || MODE == 6)
                          ? (size_t)bz * wstride
                          : (size_t)e * wstride + (size_t)zq * Kdim * N;
    const unsigned short* W  = Wp + woff;
    const unsigned short* Wl = SPLIT ? (Wlo + woff) : nullptr;
    const float* bptr = (MODE == 1) ? bias + (size_t)e * bstride
                      : (MODE == 2 || MODE == 6) ? bias + (size_t)bz * bstride : nullptr;
    const int acol = acol0 + zq * Kdim;

    constexpr int ABUF = SPLIT ? 8192 : 4096;
    __shared__ unsigned short Alds[NBUF][ABUF];   // A: [row][4 slots][8], slot-swizzled
    __shared__ unsigned short Blds[NBUF][ABUF];   // B: [kg][128][8]

    const int tid  = threadIdx.x;
    const int lane = tid & 63;
    const int wid  = tid >> 6;
    const int c0 = tid, c1 = tid + 256;
    const int r0 = c0 >> 2, r1 = c1 >> 2;

    auto aoff_of = [&](int r, int cq) -> size_t {
        int rr = m0 + r; if (rr >= cnt) rr = cnt - 1;
        int qg = base + rr;
        int row = AGATHER ? (rowmap[qg] >> rowshift) : qg;
        int slot = cq ^ ((r >> 1) & 3);          // pre-swizzled global source
        return (size_t)row * lda + acol + (slot << 3);
    };
    size_t aoff0 = aoff_of(r0, c0 & 3);
    size_t aoff1 = aoff_of(r1, c1 & 3);
    const unsigned short* a0 = A + aoff0;
    const unsigned short* a1 = A + aoff1;
    const unsigned short* al0 = SPLIT ? Alo + aoff0 : nullptr;
    const unsigned short* al1 = SPLIT ? Alo + aoff1 : nullptr;
    size_t boff0 = ((size_t)(c0 >> 7) * N + n0 + (c0 & 127)) * 8;
    size_t boff1 = ((size_t)(c1 >> 7) * N + n0 + (c1 & 127)) * 8;
    const unsigned short* b0 = W + boff0;
    const unsigned short* b1 = W + boff1;
    const unsigned short* bl0 = SPLIT ? Wl + boff0 : nullptr;
    const unsigned short* bl1 = SPLIT ? Wl + boff1 : nullptr;

    const int d0 = c0 * 8, d1 = c1 * 8;
    const size_t bstep = (size_t)32 * N;

    auto stage = [&](int buf) {
        glds16(a0, &Alds[buf][d0]);
        glds16(a1, &Alds[buf][d1]);
        glds16(b0, &Blds[buf][d0]);
        glds16(b1, &Blds[buf][d1]);
        if constexpr (SPLIT) {
            glds16(al0, &Alds[buf][4096 + d0]);
            glds16(al1, &Alds[buf][4096 + d1]);
            glds16(bl0, &Blds[buf][4096 + d0]);
            glds16(bl1, &Blds[buf][4096 + d1]);
            al0 += 32; al1 += 32; bl0 += bstep; bl1 += bstep;
        }
        a0 += 32; a1 += 32; b0 += bstep; b1 += bstep;
    };

    const int wm = wid >> 1, wn = wid & 1;
    const int lr = lane & 15, lg = lane >> 4;
    // read-side swizzle: rowL = wm*64+i*16+lr -> ((rowL>>1)&3) == ((lr>>1)&3)
    const int aslot = (lg ^ ((lr >> 1) & 3)) << 3;

    f32x4 acc[4][4];
#pragma unroll
    for (int i = 0; i < 4; ++i)
#pragma unroll
        for (int j = 0; j < 4; ++j) acc[i][j] = (f32x4){0.f, 0.f, 0.f, 0.f};

    const int niter = Kdim / 32;
    for (int s = 0; s < NBUF - 1; ++s) stage(s);

    int cur = 0, nxt = NBUF - 1;
    for (int it = 0; it < niter; ++it) {
        if (it + NBUF - 1 < niter) {
            stage(nxt);
            nxt = (nxt + 1 == NBUF) ? 0 : nxt + 1;
        }
        int rem = niter - 1 - it; if (rem > NBUF - 1) rem = NBUF - 1;
        rem *= (SPLIT ? 8 : 4);
        if (rem >= 8)      asm volatile("s_waitcnt vmcnt(8)" ::: "memory");
        else if (rem >= 4) asm volatile("s_waitcnt vmcnt(4)" ::: "memory");
        else               asm volatile("s_waitcnt vmcnt(0)" ::: "memory");
        __builtin_amdgcn_s_barrier();
        __builtin_amdgcn_sched_barrier(0);

        bf16x8 af[4], bfr[4];
#pragma unroll
        for (int i = 0; i < 4; ++i)
            af[i] = *(const bf16x8*)&Alds[cur][(wm * 64 + i * 16 + lr) * 32 + aslot];
#pragma unroll
        for (int i = 0; i < 4; ++i)
            bfr[i] = *(const bf16x8*)&Blds[cur][((lg << 7) + wn * 64 + i * 16 + lr) * 8];
#pragma unroll
        for (int mi = 0; mi < 4; ++mi)
#pragma unroll
            for (int ni = 0; ni < 4; ++ni)
                acc[mi][ni] = __builtin_amdgcn_mfma_f32_16x16x32_bf16(af[mi], bfr[ni], acc[mi][ni], 0, 0, 0);
        if constexpr (SPLIT) {
            bf16x8 afl[4], bfl[4];
#pragma unroll
            for (int i = 0; i < 4; ++i)
                afl[i] = *(const bf16x8*)&Alds[cur][4096 + (wm * 64 + i * 16 + lr) * 32 + aslot];
#pragma unroll
            for (int i = 0; i < 4; ++i)
                bfl[i] = *(const bf16x8*)&Blds[cur][4096 + ((lg << 7) + wn * 64 + i * 16 + lr) * 8];
#pragma unroll
            for (int mi = 0; mi < 4; ++mi)
#pragma unroll
                for (int ni = 0; ni < 4; ++ni) {
                    acc[mi][ni] = __builtin_amdgcn_mfma_f32_16x16x32_bf16(af[mi],  bfl[ni], acc[mi][ni], 0, 0, 0);
                    acc[mi][ni] = __builtin_amdgcn_mfma_f32_16x16x32_bf16(afl[mi], bfr[ni], acc[mi][ni], 0, 0, 0);
                }
        }
        __builtin_amdgcn_sched_barrier(0);
        __builtin_amdgcn_s_barrier();
        cur = (cur + 1 == NBUF) ? 0 : cur + 1;
    }

    float bv[4];
#pragma unroll
    for (int ni = 0; ni < 4; ++ni)
        bv[ni] = (MODE == 1 || MODE == 2 || MODE == 6)
                   ? bptr[n0 + wn * 64 + ni * 16 + lr] : 0.f;

#pragma unroll
    for (int mi = 0; mi < 4; ++mi) {
        int rbase = m0 + wm * 64 + mi * 16 + lg * 4;
#pragma unroll
        for (int rg = 0; rg < 4; ++rg) {
            int r = rbase + rg;
            if (r >= cnt) continue;
            int q = base + r;
#pragma unroll
            for (int ni = 0; ni < 4; ++ni) {
                int col = n0 + wn * 64 + ni * 16 + lr;
                float v = acc[mi][ni][rg] + bv[ni];
                if (MODE == 1) {
                    Cb[(size_t)q * ldc + col] = f2bf(v);
                } else if (MODE == 4) {
                    Cf[((size_t)zq * B_TOK + q) * ldc + col] = v;
                } else if (MODE == 5) {
                    Cf[((size_t)zq * NPAIR + q) * ldc + col] = v;
                } else if (MODE == 6) {
                    int p = rowmap[q];
                    Cb[((size_t)zq * NPAIR + q) * ldc + col]
                        = f2bf(pw[p] * apply_act(v, zq));
                } else {  // MODE 2 fallback
                    int p = rowmap[q];
                    atomicAdd(outp + ((size_t)zq * B_TOK + (p >> 1)) * D_DIM + col,
                              pw[p] * apply_act(v, zq));
                }
            }
        }
    }
}

extern "C" void kernel_launch(void* const* d_in, const int* in_sizes, int n_in,
                              void* d_out, int out_size, void* d_ws, size_t ws_size,
                              hipStream_t stream) {
    const float* h         = (const float*)d_in[0];
    const float* x         = (const float*)d_in[1];
    const int*   lidx      = (const int*)d_in[2];
    const float* layer_emb = (const float*)d_in[3];
    const float* phase_emb = (const float*)d_in[4];
    const float* Wr1       = (const float*)d_in[5];
    const float* br1       = (const float*)d_in[6];
    const float* lnr_g     = (const float*)d_in[7];
    const float* lnr_b     = (const float*)d_in[8];
    const float* Wr2       = (const float*)d_in[9];
    const float* br2       = (const float*)d_in[10];
    const float* W1        = (const float*)d_in[11];
    const float* b1        = (const float*)d_in[12];
    const float* ln1g      = (const float*)d_in[13];
    const float* ln1b      = (const float*)d_in[14];
    const float* W2        = (const float*)d_in[15];
    const float* b2        = (const float*)d_in[16];
    const float* Wa        = (const float*)d_in[17];
    const float* ba        = (const float*)d_in[18];
    const float* Wb_       = (const float*)d_in[19];
    const float* bbv       = (const float*)d_in[20];
    const float* Wg        = (const float*)d_in[21];
    const float* bg        = (const float*)d_in[22];
    const float* Wv        = (const float*)d_in[23];
    const float* bv        = (const float*)d_in[24];
    float* out = (float*)d_out;

    char* ws = (char*)d_ws;
    size_t off = 0;
    auto alloc = [&](size_t nb) { void* p = ws + off; off = (off + nb + 255) & ~(size_t)255; return p; };
    float*          rconstp = (float*)alloc(RH_DIM * 4);
    float*          pair_w  = (float*)alloc(NPAIR * 4);
    int*            counts  = (int*)alloc(64);
    int*            offs    = (int*)alloc(64);
    int*            lists   = (int*)alloc((size_t)E_NUM * B_TOK * 4);
    int*            rowmap  = (int*)alloc(NPAIR * 4);
    int*            row_e   = (int*)alloc(NPAIR * 4);
    int*            qof     = (int*)alloc(NPAIR * 4);
    float*          bcat    = (float*)alloc((size_t)4 * E_NUM * D_DIM * 4);        // 128 KB
    unsigned short* hx_hi   = (unsigned short*)alloc((size_t)B_TOK * 2048 * 2);    // 16 MiB
    unsigned short* hid_bf  = (unsigned short*)alloc((size_t)NPAIR * HID_DIM * 2); // 8 MiB
    char*           featsR  = (char*)alloc((size_t)NPAIR * 4096 * 2);              // 64 MiB
    unsigned short* wsc_hi  = (unsigned short*)alloc((size_t)4 * E_NUM * D_DIM * D_DIM * 2); // 64 MiB
    unsigned short* wsc_lo  = (unsigned short*)alloc((size_t)2048 * RH_DIM * 2);   // 1 MiB
    unsigned short* sel     = (unsigned short*)alloc((size_t)4 * NPAIR * D_DIM * 2); // 64 MiB
    const bool use_sel = (off <= ws_size);
    // aliases inside featsR (disjoint lifetimes):
    float*          Pf      = (float*)featsR;                                  // [0,16M)  dead after k_route
    float*          hidp    = (float*)(featsR + ((size_t)16 << 20));           // [16,48M) dead after k_lngelu
    unsigned short* hx_lo   = (unsigned short*)(featsR + ((size_t)48 << 20));  // [48,64M) dead after routing mm
    unsigned short* feats   = (unsigned short*)featsR;                         // layer2 output (full 64M)

    if (!use_sel) (void)hipMemsetAsync(d_out, 0, (size_t)out_size * 4, stream);
    (void)hipMemsetAsync(counts, 0, 64, stream);
    (void)hipMemcpyAsync(bcat + 0 * E_NUM * D_DIM, ba,  (size_t)E_NUM * D_DIM * 4, hipMemcpyDeviceToDevice, stream);
    (void)hipMemcpyAsync(bcat + 1 * E_NUM * D_DIM, bbv, (size_t)E_NUM * D_DIM * 4, hipMemcpyDeviceToDevice, stream);
    (void)hipMemcpyAsync(bcat + 2 * E_NUM * D_DIM, bg,  (size_t)E_NUM * D_DIM * 4, hipMemcpyDeviceToDevice, stream);
    (void)hipMemcpyAsync(bcat + 3 * E_NUM * D_DIM, bv,  (size_t)E_NUM * D_DIM * 4, hipMemcpyDeviceToDevice, stream);

    // ---- routing path: split-K x4 partials (deterministic fixed-order combine)
    k_hxbf<<<4096, 256, 0, stream>>>(h, x, hx_hi, hx_lo);
    k_convW<true><<<dim3(1, 256, 1), 256, 0, stream>>>(Wr1, nullptr, nullptr, nullptr,
                                                       wsc_hi, wsc_lo, 2048, RH_DIM, 1);
    k_rconst<<<1, 256, 0, stream>>>(layer_emb, phase_emb, lidx, Wr1, br1, rconstp);
    k_mm<4, true, false, 2><<<dim3(2, 32, 4), 256, 0, stream>>>(
        hx_hi, hx_lo, 2048, 0, 0, wsc_hi, wsc_lo, 0, nullptr, 0,
        Pf, nullptr, RH_DIM, nullptr, nullptr, nullptr, B_TOK,
        RH_DIM, 512, 1, nullptr, nullptr);
    k_route<<<B_TOK, 256, 0, stream>>>(Pf, rconstp, lnr_g, lnr_b, Wr2, br2,
                                       pair_w, lists, counts);
    k_offs<<<1, 64, 0, stream>>>(counts, offs);
    k_meta<<<NPAIR / 256, 256, 0, stream>>>(offs, lists, rowmap, row_e, qof);

    // ---- layer1 (split-K x2, sorted C): hidp[kh][q](512) = hx[token] @ W1[e]
    k_convW<false><<<dim3(2, 256, 8), 256, 0, stream>>>(W1, nullptr, nullptr, nullptr,
                                                        wsc_hi, nullptr, 2048, HID_DIM, 8);
    k_mm<5, false, true, 3><<<dim3(4, 32, 16), 256, 0, stream>>>(
        hx_hi, nullptr, 2048, 1, 0, wsc_hi, nullptr, (size_t)2048 * HID_DIM, nullptr, 0,
        hidp, nullptr, HID_DIM, offs, counts, rowmap, 0,
        HID_DIM, 1024, 8, nullptr, nullptr);
    k_lngelu<<<NPAIR, 256, 0, stream>>>(hidp, b1, hid_bf, row_e, ln1g, ln1b);

    // ---- layer2: feats[q](4096) = hid_bf[q] @ W2[e] + b2[e]  (bf16 out, sorted)
    k_convW<false><<<dim3(16, 64, 8), 256, 0, stream>>>(W2, nullptr, nullptr, nullptr,
                                                        wsc_hi, nullptr, HID_DIM, 4096, 8);
    k_mm<1, false, false, 3><<<dim3(32, 32, 8), 256, 0, stream>>>(
        hid_bf, nullptr, HID_DIM, 0, 0, wsc_hi, nullptr, (size_t)HID_DIM * 4096, b2, 4096,
        nullptr, feats, 4096, offs, counts, nullptr, 0,
        4096, HID_DIM, 8, nullptr, nullptr);

    // ---- layer3, single launch (o,e fused; z = o*8+e)
    k_convW<false><<<dim3(4, 128, 32), 256, 0, stream>>>(Wa, Wb_, Wg, Wv,
                                                         wsc_hi, nullptr, D_DIM, D_DIM, 8);
    if (use_sel) {
        k_mm<6, false, false, 3><<<dim3(8, 32, 32), 256, 0, stream>>>(
            feats, nullptr, 4096, 0, 0, wsc_hi, nullptr, (size_t)D_DIM * D_DIM, bcat, D_DIM,
            nullptr, sel, D_DIM, offs, counts, rowmap, 0,
            D_DIM, D_DIM, 8, nullptr, pair_w);
        k_comb<<<dim3(B_TOK, 4), 256, 0, stream>>>(sel, qof, out);
    } else {
        k_mm<2, false, false, 3><<<dim3(8, 32, 32), 256, 0, stream>>>(
            feats, nullptr, 4096, 0, 0, wsc_hi, nullptr, (size_t)D_DIM * D_DIM, bcat, D_DIM,
            nullptr, nullptr, 0, offs, counts, rowmap, 0,
            D_DIM, D_DIM, 8, out, pair_w);
    }
}